// Round 7
// baseline (506.262 us; speedup 1.0000x reference)
//
#include <hip/hip_runtime.h>
#include <hip/hip_bf16.h>
#include <cstdint>

typedef unsigned short u16;
typedef u16  u16x8 __attribute__((ext_vector_type(8)));
typedef short s16x8 __attribute__((ext_vector_type(8)));
typedef float f32x4 __attribute__((ext_vector_type(4)));

#define PI_F 3.14159265358979323846f
#define PD(i) ((i) + ((i) >> 5))

static __device__ __forceinline__ u16 f2bf(float f) {
    union { float f; unsigned u; } v; v.f = f;
    unsigned r = v.u + 0x7fffu + ((v.u >> 16) & 1u);
    return (u16)(r >> 16);
}
static __device__ __forceinline__ float bf2f(u16 h) {
    union { unsigned u; float f; } v; v.u = ((unsigned)h) << 16;
    return v.f;
}

__device__ __forceinline__ void gl_lds16(const u16* g, u16* l) {
    __builtin_amdgcn_global_load_lds(
        (const __attribute__((address_space(1))) unsigned int*)g,
        (__attribute__((address_space(3))) unsigned int*)l, 16, 0, 0);
}

// ---------------------------------------------------------------------------
// f32 -> bf16 convert (vectorized)
// ---------------------------------------------------------------------------
__global__ __launch_bounds__(256) void cvt_bf16(const float* __restrict__ in,
                                                u16* __restrict__ out, int n8) {
    int i = blockIdx.x * 256 + threadIdx.x;
    if (i >= n8) return;
    float4 a = ((const float4*)in)[2 * i];
    float4 b = ((const float4*)in)[2 * i + 1];
    u16x8 v;
    v[0] = f2bf(a.x); v[1] = f2bf(a.y); v[2] = f2bf(a.z); v[3] = f2bf(a.w);
    v[4] = f2bf(b.x); v[5] = f2bf(b.y); v[6] = f2bf(b.z); v[7] = f2bf(b.w);
    ((u16x8*)out)[i] = v;
}

// ---------------------------------------------------------------------------
// Expand quaternion weight W[4][512][in_q] into real matrix E[2048][4*in_q] bf16
// ---------------------------------------------------------------------------
__global__ void build_E(const float* __restrict__ W, u16* __restrict__ E, int logK) {
    const int K = 1 << logK;
    int idx = blockIdx.x * 256 + threadIdx.x;
    if (idx >= (2048 << logK)) return;
    int n = idx >> logK, k = idx & (K - 1);
    int o = n >> 2, c = n & 3, i = k >> 2, cp = k & 3;
    const int   qm[4][4] = {{0,1,2,3},{1,0,3,2},{2,3,0,1},{3,2,1,0}};
    const float qs[4][4] = {{1.f,-1.f,-1.f,-1.f},{1.f,1.f,1.f,-1.f},
                            {1.f,-1.f,1.f,1.f},{1.f,1.f,-1.f,1.f}};
    int in_q = K >> 2;
    float w = W[(size_t)qm[c][cp] * 512 * in_q + (size_t)o * in_q + i] * qs[c][cp];
    E[idx] = f2bf(w);
}

// ---------------------------------------------------------------------------
// Twiddle + phase tables: W[i] = cis(-pi*i/1024), i in [0,1024);
// PH[i] = atan(log(i/2048 + 1e-6)), i in [0,1024].
// ---------------------------------------------------------------------------
__global__ __launch_bounds__(256) void build_tabs(float* __restrict__ wre,
                                                  float* __restrict__ wim,
                                                  float* __restrict__ ph) {
    int i = blockIdx.x * 256 + threadIdx.x;
    if (i < 1024) {
        float a = (-PI_F / 1024.0f) * (float)i;
        wre[i] = cosf(a);
        wim[i] = sinf(a);
    }
    if (i <= 1024) {
        ph[i] = atanf(logf((float)i * (1.0f / 2048.0f) + 1e-6f));
    }
}

// ---------------------------------------------------------------------------
// bf16 MFMA GEMM (m97 structure, proven): out = A[M][K] * E[N][K]^T + bias
// 128x128 tile, BK=64, 4 waves (2x2). 1D grid of 1024 blocks remapped to
// (bx<16, by<64) via bijective XCD-chunked 4x4 super-tiles: each super-tile
// touches 4 A-panels + 4 E-panels (4 MB) = L2-resident per XCD. [T1/m204]
// OUTMODE 0: bf16 [m][n]; 1: f32 [m][n]; 2: bf16 transposed [b][n][s]
// ---------------------------------------------------------------------------
template<int K, int OUTMODE>
__global__ __launch_bounds__(256) void gemm2(const u16* __restrict__ A,
                                             const u16* __restrict__ E,
                                             const float* __restrict__ bias,
                                             void* __restrict__ outp) {
    __shared__ u16 As[128 * 64];
    __shared__ u16 Bs[128 * 64];
    const int t    = threadIdx.x;
    const int lane = t & 63, wave = t >> 6;
    const int wr   = wave >> 1, wc = wave & 1;
    const int lr   = lane & 15, kg = lane >> 4;
    const int l7   = lr & 7;

    // XCD-chunked 4x4 super-tile decode (nwg=1024, 8 XCDs, NBX=16, NBY=64)
    const int bid = blockIdx.x;
    const int xcd = bid & 7, p = bid >> 3;       // p in [0,128)
    const int st  = xcd * 8 + (p >> 4);          // supertile id in [0,64)
    const int w   = p & 15;
    const int bx  = (st & 3) * 4 + (w & 3);      // [0,16)
    const int by  = (st >> 2) * 4 + (w >> 2);    // [0,64)
    const int m0  = by * 128;
    const int n0  = bx * 128;

    f32x4 acc[4][4];
#pragma unroll
    for (int i = 0; i < 4; ++i)
#pragma unroll
        for (int j = 0; j < 4; ++j) acc[i][j] = (f32x4){0.f, 0.f, 0.f, 0.f};

    const int arow = wr * 64 + lr;
    const int brow = wc * 64 + lr;

    for (int k0 = 0; k0 < K; k0 += 64) {
#pragma unroll
        for (int c = 0; c < 4; ++c) {
            int idx = t + c * 256;
            int row = idx >> 3, sl = idx & 7;
            int gsl = sl ^ (row & 7);          // inverse-swizzled global source
            gl_lds16(A + (size_t)(m0 + row) * K + k0 + gsl * 8, &As[idx * 8]);
            gl_lds16(E + (size_t)(n0 + row) * K + k0 + gsl * 8, &Bs[idx * 8]);
        }
        __syncthreads();
#pragma unroll
        for (int ks = 0; ks < 2; ++ks) {
            const int slot = (ks * 4 + kg) ^ l7;   // swizzled read slot
            s16x8 av[4], bv[4];
#pragma unroll
            for (int mi = 0; mi < 4; ++mi)
                av[mi] = *(const s16x8*)&As[(arow + mi * 16) * 64 + slot * 8];
#pragma unroll
            for (int ni = 0; ni < 4; ++ni)
                bv[ni] = *(const s16x8*)&Bs[(brow + ni * 16) * 64 + slot * 8];
#pragma unroll
            for (int mi = 0; mi < 4; ++mi)
#pragma unroll
                for (int ni = 0; ni < 4; ++ni)
                    acc[mi][ni] = __builtin_amdgcn_mfma_f32_16x16x32_bf16(
                        av[mi], bv[ni], acc[mi][ni], 0, 0, 0);
        }
        __syncthreads();
    }

#pragma unroll
    for (int ni = 0; ni < 4; ++ni) {
        int n = n0 + wc * 64 + ni * 16 + lr;
        float bvl = bias[n];
#pragma unroll
        for (int mi = 0; mi < 4; ++mi) {
#pragma unroll
            for (int r = 0; r < 4; ++r) {
                int m = m0 + wr * 64 + mi * 16 + kg * 4 + r;
                float val = acc[mi][ni][r] + bvl;
                if constexpr (OUTMODE == 0) {
                    ((u16*)outp)[(size_t)m * 2048 + n] = f2bf(val);
                } else if constexpr (OUTMODE == 1) {
                    ((float*)outp)[(size_t)m * 2048 + n] = val;
                } else {
                    int b = m >> 11, s = m & 2047;
                    ((u16*)outp)[((size_t)b * 2048 + n) * 2048 + s] = f2bf(val);
                }
            }
        }
    }
}

// ---------------------------------------------------------------------------
// In-place FFT, 2048 complex in padded LDS, bit-reversed input, natural
// output. Radix-4 fused passes + final radix-2. Twiddles from LDS table
// wre/wim: stage-h twiddle exp(-i*pi*j/h) = W[j<<(10-lh)].
// ---------------------------------------------------------------------------
__device__ void fft2048(float* re, float* im, int t,
                        const float* __restrict__ wre,
                        const float* __restrict__ wim) {
#pragma unroll 1
    for (int lh = 0; lh < 10; lh += 2) {
        const int h = 1 << lh;
        const int j = t & (h - 1);           // u-invariant
        const float w2r = wre[j << (9 - lh)], w2i = wim[j << (9 - lh)];
        const float w1r = wre[j << (10 - lh)], w1i = wim[j << (10 - lh)];
        const float w3r = w2i, w3i = -w2r;   // -i * W2
        __syncthreads();
#pragma unroll
        for (int u = 0; u < 2; ++u) {
            int vidx = t + u * 256;          // 0..511 radix-4 butterflies
            int i0 = ((vidx >> lh) << (lh + 2)) | j;
            int p0 = PD(i0), p1 = PD(i0 + h), p2 = PD(i0 + 2 * h), p3 = PD(i0 + 3 * h);
            float ar = re[p0], ai = im[p0];
            float br = re[p1], bi = im[p1];
            float cr = re[p2], ci = im[p2];
            float dr = re[p3], di = im[p3];
            float tbr = w1r * br - w1i * bi, tbi = w1r * bi + w1i * br;
            float tdr = w1r * dr - w1i * di, tdi = w1r * di + w1i * dr;
            float a1r = ar + tbr, a1i = ai + tbi;
            float b1r = ar - tbr, b1i = ai - tbi;
            float c1r = cr + tdr, c1i = ci + tdi;
            float d1r = cr - tdr, d1i = ci - tdi;
            float tcr = w2r * c1r - w2i * c1i, tci = w2r * c1i + w2i * c1r;
            float ter = w3r * d1r - w3i * d1i, tei = w3r * d1i + w3i * d1r;
            re[p0] = a1r + tcr; im[p0] = a1i + tci;
            re[p2] = a1r - tcr; im[p2] = a1i - tci;
            re[p1] = b1r + ter; im[p1] = b1i + tei;
            re[p3] = b1r - ter; im[p3] = b1i - tei;
        }
    }
    // final radix-2 stage, half = 1024, twiddle = W[j]
    __syncthreads();
#pragma unroll
    for (int u = 0; u < 4; ++u) {
        int j = t + u * 256;
        float wr = wre[j], wi = wim[j];
        int p0 = PD(j), p1 = PD(j + 1024);
        float xr = re[p1], xi = im[p1];
        float tr = wr * xr - wi * xi;
        float ti = wr * xi + wi * xr;
        float yr = re[p0], yi = im[p0];
        re[p1] = yr - tr; im[p1] = yi - ti;
        re[p0] = yr + tr; im[p0] = yi + ti;
    }
    __syncthreads();
}

// ---------------------------------------------------------------------------
// Spectral attention: 2 channels/block, Q+iK packed forward FFTs (2),
// Hermitian-packed inverse (1). Twiddles/phases from tables. Vt *= w in place.
// ---------------------------------------------------------------------------
__global__ __launch_bounds__(256) void spectral3(const u16* __restrict__ Qt,
                                                 const u16* __restrict__ Kt,
                                                 u16* __restrict__ Vt,
                                                 const float* __restrict__ alpha,
                                                 const float* __restrict__ gwre,
                                                 const float* __restrict__ gwim,
                                                 const float* __restrict__ gph) {
    __shared__ float zre[2112], zim[2112];
    __shared__ float wre[1024], wim[1024];
    const int t  = threadIdx.x;
    const int b  = blockIdx.x >> 10;
    const int cp = blockIdx.x & 1023;
    const int c0 = cp * 2;
    const size_t base0 = ((size_t)b * 2048 + c0) * 2048;
    const size_t base1 = base0 + 2048;

#pragma unroll
    for (int i = 0; i < 4; ++i) {
        wre[t + i * 256] = gwre[t + i * 256];
        wim[t + i * 256] = gwim[t + i * 256];
    }

    float ph[4];
    float PH1r[4], PH1i[4], PH2r[4], PH2i[4];
    float ph24 = 0.f, PH24_1 = 0.f, PH24_2 = 0.f;

#pragma unroll
    for (int ch = 0; ch < 2; ++ch) {
        const size_t base = ch ? base1 : base0;
        const u16* Qp = Qt + base;
        const u16* Kp = Kt + base;
        __syncthreads();    // prior LDS consumers done (also covers wtab load)
#pragma unroll
        for (int u = 0; u < 8; ++u) {
            int s = t + u * 256;
            int r = __brev((unsigned)s) >> 21;
            zre[PD(r)] = bf2f(Qp[s]);
            zim[PD(r)] = bf2f(Kp[s]);
        }
        fft2048(zre, zim, t, wre, wim);
        const float ac = alpha[c0 + ch];
#pragma unroll
        for (int u = 0; u < 4; ++u) {
            int k = t + u * 256;
            int m = (2048 - k) & 2047;
            float ar = zre[PD(k)], ai = zim[PD(k)];
            float br = zre[PD(m)], bi = zim[PD(m)];
            float qr = 0.5f * (ar + br), qi = 0.5f * (ai - bi);
            float kr = 0.5f * (ai + bi), ki = 0.5f * (br - ar);
            float cr = qr * kr + qi * ki;
            float ci = qi * kr - qr * ki;
            if (ch == 0) ph[u] = gph[min(k, 2048 - k)];
            float fr, fi;
            __sincosf(ph[u] * ac, &fi, &fr);
            float Pkr = cr * fr - ci * fi, Pki = cr * fi + ci * fr;
            float qr2 = 0.5f * (br + ar), qi2 = 0.5f * (bi - ai);
            float kr2 = 0.5f * (bi + ai), ki2 = 0.5f * (ar - br);
            float cr2 = qr2 * kr2 + qi2 * ki2;
            float ci2 = qi2 * kr2 - qr2 * ki2;
            float Pmr = cr2 * fr - ci2 * fi, Pmi = cr2 * fi + ci2 * fr;
            float hr = 0.5f * (Pkr + Pmr), hi = 0.5f * (Pki - Pmi);
            if (ch == 0) { PH1r[u] = hr; PH1i[u] = hi; }
            else         { PH2r[u] = hr; PH2i[u] = hi; }
        }
        if (t == 0) {
            float ar = zre[PD(1024)], ai = zim[PD(1024)];
            float cr = ar * ai;
            if (ch == 0) ph24 = gph[1024];
            float fr, fi;
            __sincosf(ph24 * ac, &fi, &fr);
            if (ch == 0) PH24_1 = cr * fr; else PH24_2 = cr * fr;
        }
    }

    __syncthreads();
#pragma unroll
    for (int u = 0; u < 4; ++u) {
        int k = t + u * 256;
        int m = (2048 - k) & 2047;
        int rk = __brev((unsigned)k) >> 21;
        int rm = __brev((unsigned)m) >> 21;
        zre[PD(rk)] = PH1r[u] - PH2i[u];
        zim[PD(rk)] = PH1i[u] + PH2r[u];
        zre[PD(rm)] = PH1r[u] + PH2i[u];
        zim[PD(rm)] = PH2r[u] - PH1i[u];
    }
    if (t == 0) {
        zre[PD(1)] = PH24_1;
        zim[PD(1)] = PH24_2;
    }
    fft2048(zre, zim, t, wre, wim);

#pragma unroll
    for (int u = 0; u < 8; ++u) {
        int s = t + u * 256;
        int j = (2048 - s) & 2047;
        float w0 = zre[PD(j)] * (1.0f / 2048.0f);
        float w1 = zim[PD(j)] * (1.0f / 2048.0f);
        Vt[base0 + s] = f2bf(bf2f(Vt[base0 + s]) * w0);
        Vt[base1 + s] = f2bf(bf2f(Vt[base1 + s]) * w1);
    }
}

// ---------------------------------------------------------------------------
// Transpose [B][C][S] bf16 -> [(b,s)][c] bf16
// ---------------------------------------------------------------------------
__global__ __launch_bounds__(256) void transpose_k(const u16* __restrict__ in,
                                                   u16* __restrict__ out) {
    __shared__ u16 tile[32][33];
    int b = blockIdx.z;
    int c0 = blockIdx.x * 32, s0 = blockIdx.y * 32;
    int tx = threadIdx.x, ty = threadIdx.y;
#pragma unroll
    for (int dy = 0; dy < 32; dy += 8)
        tile[ty + dy][tx] = in[((size_t)b * 2048 + c0 + ty + dy) * 2048 + s0 + tx];
    __syncthreads();
#pragma unroll
    for (int dy = 0; dy < 32; dy += 8)
        out[((size_t)b * 2048 + s0 + ty + dy) * 2048 + c0 + tx] = tile[tx][ty + dy];
}

// ---------------------------------------------------------------------------
extern "C" void kernel_launch(void* const* d_in, const int* in_sizes, int n_in,
                              void* d_out, int out_size, void* d_ws, size_t ws_size,
                              hipStream_t stream) {
    const float* query = (const float*)d_in[0];
    const float* key   = (const float*)d_in[1];
    const float* value = (const float*)d_in[2];
    const float* Wq    = (const float*)d_in[3];
    const float* bq    = (const float*)d_in[4];
    const float* Wk    = (const float*)d_in[5];
    const float* bk    = (const float*)d_in[6];
    const float* Wv    = (const float*)d_in[7];
    const float* bv    = (const float*)d_in[8];
    const float* alpha = (const float*)d_in[9];
    const float* Wint  = (const float*)d_in[10];
    const float* bint  = (const float*)d_in[11];
    const float* Wfin  = (const float*)d_in[12];
    const float* bfin  = (const float*)d_in[13];
    const float* Wout  = (const float*)d_in[14];
    const float* bout  = (const float*)d_in[15];

    char* ws = (char*)d_ws;
    size_t off = 0;
    auto alloc = [&](size_t bytes) -> void* {
        void* p = ws + off;
        off += (bytes + 255) & ~(size_t)255;
        return p;
    };
    u16* Eq   = (u16*)alloc((size_t)2048 * 512 * 2);
    u16* Ek   = (u16*)alloc((size_t)2048 * 512 * 2);
    u16* Ev   = (u16*)alloc((size_t)2048 * 512 * 2);
    u16* Eint = (u16*)alloc((size_t)2048 * 2048 * 2);
    u16* Efin = (u16*)alloc((size_t)2048 * 2048 * 2);
    u16* Eout = (u16*)alloc((size_t)2048 * 2048 * 2);
    u16* Qt   = (u16*)alloc((size_t)4 * 2048 * 2048 * 2);  // [B][C][S]
    u16* Kt   = (u16*)alloc((size_t)4 * 2048 * 2048 * 2);
    u16* Vt   = (u16*)alloc((size_t)4 * 2048 * 2048 * 2);
    u16* attn = (u16*)alloc((size_t)8192 * 2048 * 2);
    float* wtr = (float*)alloc(1024 * 4);
    float* wti = (float*)alloc(1024 * 4);
    float* pht = (float*)alloc(1025 * 4);
    u16* h1   = Qt;
    u16* h2   = Kt;
    u16* Aq = attn;
    u16* Ak = attn + (size_t)8192 * 512;
    u16* Av = attn + (size_t)8192 * 1024;

    const int n8 = 8192 * 512 / 8;
    cvt_bf16<<<(n8 + 255) / 256, 256, 0, stream>>>(query, Aq, n8);
    cvt_bf16<<<(n8 + 255) / 256, 256, 0, stream>>>(key,   Ak, n8);
    cvt_bf16<<<(n8 + 255) / 256, 256, 0, stream>>>(value, Av, n8);

    build_tabs<<<5, 256, 0, stream>>>(wtr, wti, pht);

    build_E<<<(2048 * 512  + 255) / 256, 256, 0, stream>>>(Wq,   Eq,   9);
    build_E<<<(2048 * 512  + 255) / 256, 256, 0, stream>>>(Wk,   Ek,   9);
    build_E<<<(2048 * 512  + 255) / 256, 256, 0, stream>>>(Wv,   Ev,   9);
    build_E<<<(2048 * 2048 + 255) / 256, 256, 0, stream>>>(Wint, Eint, 11);
    build_E<<<(2048 * 2048 + 255) / 256, 256, 0, stream>>>(Wfin, Efin, 11);
    build_E<<<(2048 * 2048 + 255) / 256, 256, 0, stream>>>(Wout, Eout, 11);

    const int g2 = 1024;   // 1D grid, XCD super-tile decode in-kernel
    gemm2<512, 2><<<g2, 256, 0, stream>>>(Aq, Eq, bq, Qt);
    gemm2<512, 2><<<g2, 256, 0, stream>>>(Ak, Ek, bk, Kt);
    gemm2<512, 2><<<g2, 256, 0, stream>>>(Av, Ev, bv, Vt);

    spectral3<<<4096, 256, 0, stream>>>(Qt, Kt, Vt, alpha, wtr, wti, pht);

    dim3 gt(64, 64, 4);
    transpose_k<<<gt, dim3(32, 8), 0, stream>>>(Vt, attn);

    gemm2<2048, 0><<<g2, 256, 0, stream>>>(attn, Eint, bint, h1);
    gemm2<2048, 0><<<g2, 256, 0, stream>>>(h1,   Efin, bfin, h2);
    gemm2<2048, 1><<<g2, 256, 0, stream>>>(h2,   Eout, bout, (float*)d_out);
}

// Round 8
// 491.796 us; speedup vs baseline: 1.0294x; 1.0294x over previous
//
#include <hip/hip_runtime.h>
#include <hip/hip_bf16.h>
#include <cstdint>

typedef unsigned short u16;
typedef u16  u16x8 __attribute__((ext_vector_type(8)));
typedef short s16x8 __attribute__((ext_vector_type(8)));
typedef float f32x4 __attribute__((ext_vector_type(4)));

#define PI_F 3.14159265358979323846f
#define PD(i) ((i) + ((i) >> 5))

static __device__ __forceinline__ u16 f2bf(float f) {
    union { float f; unsigned u; } v; v.f = f;
    unsigned r = v.u + 0x7fffu + ((v.u >> 16) & 1u);
    return (u16)(r >> 16);
}
static __device__ __forceinline__ float bf2f(u16 h) {
    union { unsigned u; float f; } v; v.u = ((unsigned)h) << 16;
    return v.f;
}

__device__ __forceinline__ void gl_lds16(const u16* g, u16* l) {
    __builtin_amdgcn_global_load_lds(
        (const __attribute__((address_space(1))) unsigned int*)g,
        (__attribute__((address_space(3))) unsigned int*)l, 16, 0, 0);
}

// ---------------------------------------------------------------------------
// f32 -> bf16 convert (vectorized)
// ---------------------------------------------------------------------------
__global__ __launch_bounds__(256) void cvt_bf16(const float* __restrict__ in,
                                                u16* __restrict__ out, int n8) {
    int i = blockIdx.x * 256 + threadIdx.x;
    if (i >= n8) return;
    float4 a = ((const float4*)in)[2 * i];
    float4 b = ((const float4*)in)[2 * i + 1];
    u16x8 v;
    v[0] = f2bf(a.x); v[1] = f2bf(a.y); v[2] = f2bf(a.z); v[3] = f2bf(a.w);
    v[4] = f2bf(b.x); v[5] = f2bf(b.y); v[6] = f2bf(b.z); v[7] = f2bf(b.w);
    ((u16x8*)out)[i] = v;
}

// ---------------------------------------------------------------------------
// Expand quaternion weight W[4][512][in_q] into real matrix E[2048][4*in_q] bf16
// ---------------------------------------------------------------------------
__global__ void build_E(const float* __restrict__ W, u16* __restrict__ E, int logK) {
    const int K = 1 << logK;
    int idx = blockIdx.x * 256 + threadIdx.x;
    if (idx >= (2048 << logK)) return;
    int n = idx >> logK, k = idx & (K - 1);
    int o = n >> 2, c = n & 3, i = k >> 2, cp = k & 3;
    const int   qm[4][4] = {{0,1,2,3},{1,0,3,2},{2,3,0,1},{3,2,1,0}};
    const float qs[4][4] = {{1.f,-1.f,-1.f,-1.f},{1.f,1.f,1.f,-1.f},
                            {1.f,-1.f,1.f,1.f},{1.f,1.f,-1.f,1.f}};
    int in_q = K >> 2;
    float w = W[(size_t)qm[c][cp] * 512 * in_q + (size_t)o * in_q + i] * qs[c][cp];
    E[idx] = f2bf(w);
}

// ---------------------------------------------------------------------------
// Tables: per-pass twiddle sub-tables (contiguous, conflict-free) + phases.
// Pass lh in {1,3,5,7,9}, h=2^lh: sub[j] = cis(-pi*j/(2h)), j in [0,h).
// Offsets: lh=1:0(2), lh=3:2(8), lh=5:10(32), lh=7:42(128), lh=9:170(512).
// PH[i] = atan(log(i/2048 + 1e-6)), i in [0,1024].
// ---------------------------------------------------------------------------
__global__ __launch_bounds__(256) void build_tabs(float2* __restrict__ gws,
                                                  float* __restrict__ ph) {
    int i = blockIdx.x * 256 + threadIdx.x;
    if (i < 682) {
        int off, lh;
        if (i < 2)        { off = 0;   lh = 1; }
        else if (i < 10)  { off = 2;   lh = 3; }
        else if (i < 42)  { off = 10;  lh = 5; }
        else if (i < 170) { off = 42;  lh = 7; }
        else              { off = 170; lh = 9; }
        int j = i - off;
        float a = (-PI_F) * (float)j / (float)(2 << lh);
        gws[i] = make_float2(cosf(a), sinf(a));
    }
    if (i <= 1024) {
        ph[i] = atanf(logf((float)i * (1.0f / 2048.0f) + 1e-6f));
    }
}

// ---------------------------------------------------------------------------
// bf16 MFMA GEMM (m97 structure + XCD super-tiles, proven R7)
// OUTMODE 0: bf16 [m][n]; 1: f32 [m][n]; 2: bf16 transposed [b][n][s]
// ---------------------------------------------------------------------------
template<int K, int OUTMODE>
__global__ __launch_bounds__(256) void gemm2(const u16* __restrict__ A,
                                             const u16* __restrict__ E,
                                             const float* __restrict__ bias,
                                             void* __restrict__ outp) {
    __shared__ u16 As[128 * 64];
    __shared__ u16 Bs[128 * 64];
    const int t    = threadIdx.x;
    const int lane = t & 63, wave = t >> 6;
    const int wr   = wave >> 1, wc = wave & 1;
    const int lr   = lane & 15, kg = lane >> 4;
    const int l7   = lr & 7;

    // XCD-chunked 4x4 super-tile decode (nwg=1024, 8 XCDs, NBX=16, NBY=64)
    const int bid = blockIdx.x;
    const int xcd = bid & 7, p = bid >> 3;
    const int st  = xcd * 8 + (p >> 4);
    const int w   = p & 15;
    const int bx  = (st & 3) * 4 + (w & 3);
    const int by  = (st >> 2) * 4 + (w >> 2);
    const int m0  = by * 128;
    const int n0  = bx * 128;

    f32x4 acc[4][4];
#pragma unroll
    for (int i = 0; i < 4; ++i)
#pragma unroll
        for (int j = 0; j < 4; ++j) acc[i][j] = (f32x4){0.f, 0.f, 0.f, 0.f};

    const int arow = wr * 64 + lr;
    const int brow = wc * 64 + lr;

    for (int k0 = 0; k0 < K; k0 += 64) {
#pragma unroll
        for (int c = 0; c < 4; ++c) {
            int idx = t + c * 256;
            int row = idx >> 3, sl = idx & 7;
            int gsl = sl ^ (row & 7);
            gl_lds16(A + (size_t)(m0 + row) * K + k0 + gsl * 8, &As[idx * 8]);
            gl_lds16(E + (size_t)(n0 + row) * K + k0 + gsl * 8, &Bs[idx * 8]);
        }
        __syncthreads();
#pragma unroll
        for (int ks = 0; ks < 2; ++ks) {
            const int slot = (ks * 4 + kg) ^ l7;
            s16x8 av[4], bv[4];
#pragma unroll
            for (int mi = 0; mi < 4; ++mi)
                av[mi] = *(const s16x8*)&As[(arow + mi * 16) * 64 + slot * 8];
#pragma unroll
            for (int ni = 0; ni < 4; ++ni)
                bv[ni] = *(const s16x8*)&Bs[(brow + ni * 16) * 64 + slot * 8];
#pragma unroll
            for (int mi = 0; mi < 4; ++mi)
#pragma unroll
                for (int ni = 0; ni < 4; ++ni)
                    acc[mi][ni] = __builtin_amdgcn_mfma_f32_16x16x32_bf16(
                        av[mi], bv[ni], acc[mi][ni], 0, 0, 0);
        }
        __syncthreads();
    }

#pragma unroll
    for (int ni = 0; ni < 4; ++ni) {
        int n = n0 + wc * 64 + ni * 16 + lr;
        float bvl = bias[n];
#pragma unroll
        for (int mi = 0; mi < 4; ++mi) {
#pragma unroll
            for (int r = 0; r < 4; ++r) {
                int m = m0 + wr * 64 + mi * 16 + kg * 4 + r;
                float val = acc[mi][ni][r] + bvl;
                if constexpr (OUTMODE == 0) {
                    ((u16*)outp)[(size_t)m * 2048 + n] = f2bf(val);
                } else if constexpr (OUTMODE == 1) {
                    ((float*)outp)[(size_t)m * 2048 + n] = val;
                } else {
                    int b = m >> 11, s = m & 2047;
                    ((u16*)outp)[((size_t)b * 2048 + n) * 2048 + s] = f2bf(val);
                }
            }
        }
    }
}

// ---------------------------------------------------------------------------
// In-place FFT, 2048 complex in padded LDS, bit-reversed input, natural
// output. Standalone radix-2 (h=1, twiddle-free) + radix-4 passes at
// lh=1,3,5,7,9 with stride-1 sub-table twiddles. Zero sincos.
// ---------------------------------------------------------------------------
template<int LH, int OFF>
__device__ __forceinline__ void r4pass(float* re, float* im,
                                       const float2* __restrict__ wt, int t) {
    constexpr int h = 1 << LH;
    __syncthreads();
#pragma unroll
    for (int u = 0; u < 2; ++u) {
        int vidx = t + u * 256;              // 0..511
        int j = vidx & (h - 1);
        int i0 = ((vidx >> LH) << (LH + 2)) | j;
        float2 w2 = wt[OFF + j];
        float w1r = w2.x * w2.x - w2.y * w2.y;
        float w1i = 2.f * w2.x * w2.y;
        float w3r = w2.y, w3i = -w2.x;       // -i * W2
        int p0 = PD(i0), p1 = PD(i0 + h), p2 = PD(i0 + 2 * h), p3 = PD(i0 + 3 * h);
        float ar = re[p0], ai = im[p0];
        float br = re[p1], bi = im[p1];
        float cr = re[p2], ci = im[p2];
        float dr = re[p3], di = im[p3];
        float tbr = w1r * br - w1i * bi, tbi = w1r * bi + w1i * br;
        float tdr = w1r * dr - w1i * di, tdi = w1r * di + w1i * dr;
        float a1r = ar + tbr, a1i = ai + tbi;
        float b1r = ar - tbr, b1i = ai - tbi;
        float c1r = cr + tdr, c1i = ci + tdi;
        float d1r = cr - tdr, d1i = ci - tdi;
        float tcr = w2.x * c1r - w2.y * c1i, tci = w2.x * c1i + w2.y * c1r;
        float ter = w3r * d1r - w3i * d1i, tei = w3r * d1i + w3i * d1r;
        re[p0] = a1r + tcr; im[p0] = a1i + tci;
        re[p2] = a1r - tcr; im[p2] = a1i - tci;
        re[p1] = b1r + ter; im[p1] = b1i + tei;
        re[p3] = b1r - ter; im[p3] = b1i - tei;
    }
}

__device__ void fft2048(float* re, float* im, const float2* __restrict__ wt, int t) {
    __syncthreads();   // input scatter complete
#pragma unroll
    for (int u = 0; u < 4; ++u) {
        int i0 = 2 * (t + u * 256);
        int p0 = PD(i0), p1 = p0 + 1;        // PD(i0+1)=PD(i0)+1 (i0 even)
        float ar = re[p0], ai = im[p0];
        float br = re[p1], bi = im[p1];
        re[p0] = ar + br; im[p0] = ai + bi;
        re[p1] = ar - br; im[p1] = ai - bi;
    }
    r4pass<1, 0>(re, im, wt, t);
    r4pass<3, 2>(re, im, wt, t);
    r4pass<5, 10>(re, im, wt, t);
    r4pass<7, 42>(re, im, wt, t);
    r4pass<9, 170>(re, im, wt, t);
    __syncthreads();
}

// ---------------------------------------------------------------------------
// Spectral attention: 2 channels/block, Q+iK packed forward FFTs (2),
// Hermitian-packed inverse (1). Table twiddles/phases. Vt *= w in place.
// ---------------------------------------------------------------------------
__global__ __launch_bounds__(256) void spectral3(const u16* __restrict__ Qt,
                                                 const u16* __restrict__ Kt,
                                                 u16* __restrict__ Vt,
                                                 const float* __restrict__ alpha,
                                                 const float2* __restrict__ gws,
                                                 const float* __restrict__ gph) {
    __shared__ float zre[2112], zim[2112];
    __shared__ float2 wt[682];
    const int t  = threadIdx.x;
    const int b  = blockIdx.x >> 10;
    const int cp = blockIdx.x & 1023;
    const int c0 = cp * 2;
    const size_t base0 = ((size_t)b * 2048 + c0) * 2048;
    const size_t base1 = base0 + 2048;

    for (int i = t; i < 682; i += 256) wt[i] = gws[i];

    float ph[4];
    float PH1r[4], PH1i[4], PH2r[4], PH2i[4];
    float ph24 = 0.f, PH24_1 = 0.f, PH24_2 = 0.f;

#pragma unroll
    for (int ch = 0; ch < 2; ++ch) {
        const size_t base = ch ? base1 : base0;
        const u16* Qp = Qt + base;
        const u16* Kp = Kt + base;
        __syncthreads();    // prior LDS consumers done (covers wt load too)
#pragma unroll
        for (int u = 0; u < 8; ++u) {
            int s = t + u * 256;
            int r = __brev((unsigned)s) >> 21;
            zre[PD(r)] = bf2f(Qp[s]);
            zim[PD(r)] = bf2f(Kp[s]);
        }
        fft2048(zre, zim, wt, t);
        const float ac = alpha[c0 + ch];
#pragma unroll
        for (int u = 0; u < 4; ++u) {
            int k = t + u * 256;
            int m = (2048 - k) & 2047;
            float ar = zre[PD(k)], ai = zim[PD(k)];
            float br = zre[PD(m)], bi = zim[PD(m)];
            float qr = 0.5f * (ar + br), qi = 0.5f * (ai - bi);
            float kr = 0.5f * (ai + bi), ki = 0.5f * (br - ar);
            float cr = qr * kr + qi * ki;
            float ci = qi * kr - qr * ki;
            if (ch == 0) ph[u] = gph[min(k, 2048 - k)];
            float fr, fi;
            __sincosf(ph[u] * ac, &fi, &fr);
            float Pkr = cr * fr - ci * fi, Pki = cr * fi + ci * fr;
            float qr2 = 0.5f * (br + ar), qi2 = 0.5f * (bi - ai);
            float kr2 = 0.5f * (bi + ai), ki2 = 0.5f * (ar - br);
            float cr2 = qr2 * kr2 + qi2 * ki2;
            float ci2 = qi2 * kr2 - qr2 * ki2;
            float Pmr = cr2 * fr - ci2 * fi, Pmi = cr2 * fi + ci2 * fr;
            float hr = 0.5f * (Pkr + Pmr), hi = 0.5f * (Pki - Pmi);
            if (ch == 0) { PH1r[u] = hr; PH1i[u] = hi; }
            else         { PH2r[u] = hr; PH2i[u] = hi; }
        }
        if (t == 0) {
            float ar = zre[PD(1024)], ai = zim[PD(1024)];
            float cr = ar * ai;
            if (ch == 0) ph24 = gph[1024];
            float fr, fi;
            __sincosf(ph24 * ac, &fi, &fr);
            if (ch == 0) PH24_1 = cr * fr; else PH24_2 = cr * fr;
        }
    }

    __syncthreads();
#pragma unroll
    for (int u = 0; u < 4; ++u) {
        int k = t + u * 256;
        int m = (2048 - k) & 2047;
        int rk = __brev((unsigned)k) >> 21;
        int rm = __brev((unsigned)m) >> 21;
        zre[PD(rk)] = PH1r[u] - PH2i[u];
        zim[PD(rk)] = PH1i[u] + PH2r[u];
        zre[PD(rm)] = PH1r[u] + PH2i[u];
        zim[PD(rm)] = PH2r[u] - PH1i[u];
    }
    if (t == 0) {
        zre[PD(1)] = PH24_1;
        zim[PD(1)] = PH24_2;
    }
    fft2048(zre, zim, wt, t);

#pragma unroll
    for (int u = 0; u < 8; ++u) {
        int s = t + u * 256;
        int j = (2048 - s) & 2047;
        float w0 = zre[PD(j)] * (1.0f / 2048.0f);
        float w1 = zim[PD(j)] * (1.0f / 2048.0f);
        Vt[base0 + s] = f2bf(bf2f(Vt[base0 + s]) * w0);
        Vt[base1 + s] = f2bf(bf2f(Vt[base1 + s]) * w1);
    }
}

// ---------------------------------------------------------------------------
// Transpose [B][C][S] bf16 -> [(b,s)][c] bf16
// ---------------------------------------------------------------------------
__global__ __launch_bounds__(256) void transpose_k(const u16* __restrict__ in,
                                                   u16* __restrict__ out) {
    __shared__ u16 tile[32][33];
    int b = blockIdx.z;
    int c0 = blockIdx.x * 32, s0 = blockIdx.y * 32;
    int tx = threadIdx.x, ty = threadIdx.y;
#pragma unroll
    for (int dy = 0; dy < 32; dy += 8)
        tile[ty + dy][tx] = in[((size_t)b * 2048 + c0 + ty + dy) * 2048 + s0 + tx];
    __syncthreads();
#pragma unroll
    for (int dy = 0; dy < 32; dy += 8)
        out[((size_t)b * 2048 + s0 + ty + dy) * 2048 + c0 + tx] = tile[tx][ty + dy];
}

// ---------------------------------------------------------------------------
extern "C" void kernel_launch(void* const* d_in, const int* in_sizes, int n_in,
                              void* d_out, int out_size, void* d_ws, size_t ws_size,
                              hipStream_t stream) {
    const float* query = (const float*)d_in[0];
    const float* key   = (const float*)d_in[1];
    const float* value = (const float*)d_in[2];
    const float* Wq    = (const float*)d_in[3];
    const float* bq    = (const float*)d_in[4];
    const float* Wk    = (const float*)d_in[5];
    const float* bk    = (const float*)d_in[6];
    const float* Wv    = (const float*)d_in[7];
    const float* bv    = (const float*)d_in[8];
    const float* alpha = (const float*)d_in[9];
    const float* Wint  = (const float*)d_in[10];
    const float* bint  = (const float*)d_in[11];
    const float* Wfin  = (const float*)d_in[12];
    const float* bfin  = (const float*)d_in[13];
    const float* Wout  = (const float*)d_in[14];
    const float* bout  = (const float*)d_in[15];

    char* ws = (char*)d_ws;
    size_t off = 0;
    auto alloc = [&](size_t bytes) -> void* {
        void* p = ws + off;
        off += (bytes + 255) & ~(size_t)255;
        return p;
    };
    u16* Eq   = (u16*)alloc((size_t)2048 * 512 * 2);
    u16* Ek   = (u16*)alloc((size_t)2048 * 512 * 2);
    u16* Ev   = (u16*)alloc((size_t)2048 * 512 * 2);
    u16* Eint = (u16*)alloc((size_t)2048 * 2048 * 2);
    u16* Efin = (u16*)alloc((size_t)2048 * 2048 * 2);
    u16* Eout = (u16*)alloc((size_t)2048 * 2048 * 2);
    u16* Qt   = (u16*)alloc((size_t)4 * 2048 * 2048 * 2);  // [B][C][S]
    u16* Kt   = (u16*)alloc((size_t)4 * 2048 * 2048 * 2);
    u16* Vt   = (u16*)alloc((size_t)4 * 2048 * 2048 * 2);
    u16* attn = (u16*)alloc((size_t)8192 * 2048 * 2);
    float2* gws = (float2*)alloc(682 * 8);
    float*  pht = (float*)alloc(1025 * 4);
    u16* h1   = Qt;
    u16* h2   = Kt;
    u16* Aq = attn;
    u16* Ak = attn + (size_t)8192 * 512;
    u16* Av = attn + (size_t)8192 * 1024;

    const int n8 = 8192 * 512 / 8;
    cvt_bf16<<<(n8 + 255) / 256, 256, 0, stream>>>(query, Aq, n8);
    cvt_bf16<<<(n8 + 255) / 256, 256, 0, stream>>>(key,   Ak, n8);
    cvt_bf16<<<(n8 + 255) / 256, 256, 0, stream>>>(value, Av, n8);

    build_tabs<<<5, 256, 0, stream>>>(gws, pht);

    build_E<<<(2048 * 512  + 255) / 256, 256, 0, stream>>>(Wq,   Eq,   9);
    build_E<<<(2048 * 512  + 255) / 256, 256, 0, stream>>>(Wk,   Ek,   9);
    build_E<<<(2048 * 512  + 255) / 256, 256, 0, stream>>>(Wv,   Ev,   9);
    build_E<<<(2048 * 2048 + 255) / 256, 256, 0, stream>>>(Wint, Eint, 11);
    build_E<<<(2048 * 2048 + 255) / 256, 256, 0, stream>>>(Wfin, Efin, 11);
    build_E<<<(2048 * 2048 + 255) / 256, 256, 0, stream>>>(Wout, Eout, 11);

    const int g2 = 1024;   // 1D grid, XCD super-tile decode in-kernel
    gemm2<512, 2><<<g2, 256, 0, stream>>>(Aq, Eq, bq, Qt);
    gemm2<512, 2><<<g2, 256, 0, stream>>>(Ak, Ek, bk, Kt);
    gemm2<512, 2><<<g2, 256, 0, stream>>>(Av, Ev, bv, Vt);

    spectral3<<<4096, 256, 0, stream>>>(Qt, Kt, Vt, alpha, gws, pht);

    dim3 gt(64, 64, 4);
    transpose_k<<<gt, dim3(32, 8), 0, stream>>>(Vt, attn);

    gemm2<2048, 0><<<g2, 256, 0, stream>>>(attn, Eint, bint, h1);
    gemm2<2048, 0><<<g2, 256, 0, stream>>>(h1,   Efin, bfin, h2);
    gemm2<2048, 1><<<g2, 256, 0, stream>>>(h2,   Eout, bout, (float*)d_out);
}

// Round 9
// 448.730 us; speedup vs baseline: 1.1282x; 1.0960x over previous
//
#include <hip/hip_runtime.h>
#include <hip/hip_bf16.h>
#include <cstdint>

typedef unsigned short u16;
typedef u16  u16x8 __attribute__((ext_vector_type(8)));
typedef short s16x8 __attribute__((ext_vector_type(8)));
typedef float f32x4 __attribute__((ext_vector_type(4)));

#define PI_F 3.14159265358979323846f
#define PD(i) ((i) + ((i) >> 5))

static __device__ __forceinline__ u16 f2bf(float f) {
    union { float f; unsigned u; } v; v.f = f;
    unsigned r = v.u + 0x7fffu + ((v.u >> 16) & 1u);
    return (u16)(r >> 16);
}
static __device__ __forceinline__ float bf2f(u16 h) {
    union { unsigned u; float f; } v; v.u = ((unsigned)h) << 16;
    return v.f;
}

__device__ __forceinline__ void gl_lds16(const u16* g, u16* l) {
    __builtin_amdgcn_global_load_lds(
        (const __attribute__((address_space(1))) unsigned int*)g,
        (__attribute__((address_space(3))) unsigned int*)l, 16, 0, 0);
}

// ---------------------------------------------------------------------------
// f32 -> bf16 convert (vectorized)
// ---------------------------------------------------------------------------
__global__ __launch_bounds__(256) void cvt_bf16(const float* __restrict__ in,
                                                u16* __restrict__ out, int n8) {
    int i = blockIdx.x * 256 + threadIdx.x;
    if (i >= n8) return;
    float4 a = ((const float4*)in)[2 * i];
    float4 b = ((const float4*)in)[2 * i + 1];
    u16x8 v;
    v[0] = f2bf(a.x); v[1] = f2bf(a.y); v[2] = f2bf(a.z); v[3] = f2bf(a.w);
    v[4] = f2bf(b.x); v[5] = f2bf(b.y); v[6] = f2bf(b.z); v[7] = f2bf(b.w);
    ((u16x8*)out)[i] = v;
}

// ---------------------------------------------------------------------------
// Expand quaternion weight W[4][512][in_q] into real matrix E[2048][4*in_q] bf16
// ---------------------------------------------------------------------------
__global__ void build_E(const float* __restrict__ W, u16* __restrict__ E, int logK) {
    const int K = 1 << logK;
    int idx = blockIdx.x * 256 + threadIdx.x;
    if (idx >= (2048 << logK)) return;
    int n = idx >> logK, k = idx & (K - 1);
    int o = n >> 2, c = n & 3, i = k >> 2, cp = k & 3;
    const int   qm[4][4] = {{0,1,2,3},{1,0,3,2},{2,3,0,1},{3,2,1,0}};
    const float qs[4][4] = {{1.f,-1.f,-1.f,-1.f},{1.f,1.f,1.f,-1.f},
                            {1.f,-1.f,1.f,1.f},{1.f,1.f,-1.f,1.f}};
    int in_q = K >> 2;
    float w = W[(size_t)qm[c][cp] * 512 * in_q + (size_t)o * in_q + i] * qs[c][cp];
    E[idx] = f2bf(w);
}

// ---------------------------------------------------------------------------
// Tables: per-pass twiddle sub-tables (contiguous, conflict-free) + phases.
// ---------------------------------------------------------------------------
__global__ __launch_bounds__(256) void build_tabs(float2* __restrict__ gws,
                                                  float* __restrict__ ph) {
    int i = blockIdx.x * 256 + threadIdx.x;
    if (i < 682) {
        int off, lh;
        if (i < 2)        { off = 0;   lh = 1; }
        else if (i < 10)  { off = 2;   lh = 3; }
        else if (i < 42)  { off = 10;  lh = 5; }
        else if (i < 170) { off = 42;  lh = 7; }
        else              { off = 170; lh = 9; }
        int j = i - off;
        float a = (-PI_F) * (float)j / (float)(2 << lh);
        gws[i] = make_float2(cosf(a), sinf(a));
    }
    if (i <= 1024) {
        ph[i] = atanf(logf((float)i * (1.0f / 2048.0f) + 1e-6f));
    }
}

// ---------------------------------------------------------------------------
// Bias matvec: out[n] = sum_k v[k]*E[n][k] + badd[n]   (one wave per n)
// ---------------------------------------------------------------------------
__global__ __launch_bounds__(256) void matvec_E(const float* __restrict__ v,
                                                const u16* __restrict__ E,
                                                const float* __restrict__ badd,
                                                float* __restrict__ out) {
    int n    = (blockIdx.x * 256 + threadIdx.x) >> 6;
    int lane = threadIdx.x & 63;
    if (n >= 2048) return;
    const u16* row = E + (size_t)n * 2048;
    float s = 0.f;
    for (int j = lane; j < 2048; j += 64) s += v[j] * bf2f(row[j]);
#pragma unroll
    for (int o = 32; o; o >>= 1) s += __shfl_down(s, o, 64);
    if (lane == 0) out[n] = s + badd[n];
}

// ---------------------------------------------------------------------------
// bf16 MFMA GEMM (m97 structure + generic XCD super-tiles).
// Grid = 1D, NBX=16 (N=2048), NBY template (M/128). nwg = 16*NBY.
// OUTMODE 0: bf16 [m][n]; 1: f32 [m][n]; 2: bf16 transposed [n][m] (/[b][n][s])
// bias may be nullptr.
// ---------------------------------------------------------------------------
template<int K, int OUTMODE, int NBY>
__global__ __launch_bounds__(256) void gemm2(const u16* __restrict__ A,
                                             const u16* __restrict__ E,
                                             const float* __restrict__ bias,
                                             void* __restrict__ outp) {
    __shared__ u16 As[128 * 64];
    __shared__ u16 Bs[128 * 64];
    const int t    = threadIdx.x;
    const int lane = t & 63, wave = t >> 6;
    const int wr   = wave >> 1, wc = wave & 1;
    const int lr   = lane & 15, kg = lane >> 4;
    const int l7   = lr & 7;

    // XCD-chunked 4x4 super-tile decode (8 XCDs, NBX=16)
    constexpr int SPX = (4 * (NBY / 4)) / 8;     // supertiles per XCD
    const int bid = blockIdx.x;
    const int xcd = bid & 7, p = bid >> 3;
    const int st  = xcd * SPX + (p >> 4);
    const int w   = p & 15;
    const int bx  = (st & 3) * 4 + (w & 3);
    const int by  = (st >> 2) * 4 + (w >> 2);
    const int m0  = by * 128;
    const int n0  = bx * 128;

    f32x4 acc[4][4];
#pragma unroll
    for (int i = 0; i < 4; ++i)
#pragma unroll
        for (int j = 0; j < 4; ++j) acc[i][j] = (f32x4){0.f, 0.f, 0.f, 0.f};

    const int arow = wr * 64 + lr;
    const int brow = wc * 64 + lr;

    for (int k0 = 0; k0 < K; k0 += 64) {
#pragma unroll
        for (int c = 0; c < 4; ++c) {
            int idx = t + c * 256;
            int row = idx >> 3, sl = idx & 7;
            int gsl = sl ^ (row & 7);
            gl_lds16(A + (size_t)(m0 + row) * K + k0 + gsl * 8, &As[idx * 8]);
            gl_lds16(E + (size_t)(n0 + row) * K + k0 + gsl * 8, &Bs[idx * 8]);
        }
        __syncthreads();
#pragma unroll
        for (int ks = 0; ks < 2; ++ks) {
            const int slot = (ks * 4 + kg) ^ l7;
            s16x8 av[4], bv[4];
#pragma unroll
            for (int mi = 0; mi < 4; ++mi)
                av[mi] = *(const s16x8*)&As[(arow + mi * 16) * 64 + slot * 8];
#pragma unroll
            for (int ni = 0; ni < 4; ++ni)
                bv[ni] = *(const s16x8*)&Bs[(brow + ni * 16) * 64 + slot * 8];
#pragma unroll
            for (int mi = 0; mi < 4; ++mi)
#pragma unroll
                for (int ni = 0; ni < 4; ++ni)
                    acc[mi][ni] = __builtin_amdgcn_mfma_f32_16x16x32_bf16(
                        av[mi], bv[ni], acc[mi][ni], 0, 0, 0);
        }
        __syncthreads();
    }

#pragma unroll
    for (int ni = 0; ni < 4; ++ni) {
        int n = n0 + wc * 64 + ni * 16 + lr;
        float bvl = bias ? bias[n] : 0.0f;
#pragma unroll
        for (int mi = 0; mi < 4; ++mi) {
#pragma unroll
            for (int r = 0; r < 4; ++r) {
                int m = m0 + wr * 64 + mi * 16 + kg * 4 + r;
                float val = acc[mi][ni][r] + bvl;
                if constexpr (OUTMODE == 0) {
                    ((u16*)outp)[(size_t)m * 2048 + n] = f2bf(val);
                } else if constexpr (OUTMODE == 1) {
                    ((float*)outp)[(size_t)m * 2048 + n] = val;
                } else {
                    int b = m >> 11, s = m & 2047;
                    ((u16*)outp)[((size_t)b * 2048 + n) * 2048 + s] = f2bf(val);
                }
            }
        }
    }
}

// ---------------------------------------------------------------------------
// In-place FFT, 2048 complex in padded LDS, bit-reversed input, natural
// output. Radix-2 (h=1, twiddle-free) + radix-4 passes lh=1,3,5,7,9.
// ---------------------------------------------------------------------------
template<int LH, int OFF>
__device__ __forceinline__ void r4pass(float* re, float* im,
                                       const float2* __restrict__ wt, int t) {
    constexpr int h = 1 << LH;
    __syncthreads();
#pragma unroll
    for (int u = 0; u < 2; ++u) {
        int vidx = t + u * 256;
        int j = vidx & (h - 1);
        int i0 = ((vidx >> LH) << (LH + 2)) | j;
        float2 w2 = wt[OFF + j];
        float w1r = w2.x * w2.x - w2.y * w2.y;
        float w1i = 2.f * w2.x * w2.y;
        float w3r = w2.y, w3i = -w2.x;
        int p0 = PD(i0), p1 = PD(i0 + h), p2 = PD(i0 + 2 * h), p3 = PD(i0 + 3 * h);
        float ar = re[p0], ai = im[p0];
        float br = re[p1], bi = im[p1];
        float cr = re[p2], ci = im[p2];
        float dr = re[p3], di = im[p3];
        float tbr = w1r * br - w1i * bi, tbi = w1r * bi + w1i * br;
        float tdr = w1r * dr - w1i * di, tdi = w1r * di + w1i * dr;
        float a1r = ar + tbr, a1i = ai + tbi;
        float b1r = ar - tbr, b1i = ai - tbi;
        float c1r = cr + tdr, c1i = ci + tdi;
        float d1r = cr - tdr, d1i = ci - tdi;
        float tcr = w2.x * c1r - w2.y * c1i, tci = w2.x * c1i + w2.y * c1r;
        float ter = w3r * d1r - w3i * d1i, tei = w3r * d1i + w3i * d1r;
        re[p0] = a1r + tcr; im[p0] = a1i + tci;
        re[p2] = a1r - tcr; im[p2] = a1i - tci;
        re[p1] = b1r + ter; im[p1] = b1i + tei;
        re[p3] = b1r - ter; im[p3] = b1i - tei;
    }
}

__device__ void fft2048(float* re, float* im, const float2* __restrict__ wt, int t) {
    __syncthreads();
#pragma unroll
    for (int u = 0; u < 4; ++u) {
        int i0 = 2 * (t + u * 256);
        int p0 = PD(i0), p1 = p0 + 1;
        float ar = re[p0], ai = im[p0];
        float br = re[p1], bi = im[p1];
        re[p0] = ar + br; im[p0] = ai + bi;
        re[p1] = ar - br; im[p1] = ai - bi;
    }
    r4pass<1, 0>(re, im, wt, t);
    r4pass<3, 2>(re, im, wt, t);
    r4pass<5, 10>(re, im, wt, t);
    r4pass<7, 42>(re, im, wt, t);
    r4pass<9, 170>(re, im, wt, t);
    __syncthreads();
}

// ---------------------------------------------------------------------------
// Spectral attention: 2 channels/block, Q+iK packed forward FFTs (2),
// Hermitian-packed inverse (1). Table twiddles/phases. Vt *= w in place.
// ---------------------------------------------------------------------------
__global__ __launch_bounds__(256) void spectral3(const u16* __restrict__ Qt,
                                                 const u16* __restrict__ Kt,
                                                 u16* __restrict__ Vt,
                                                 const float* __restrict__ alpha,
                                                 const float2* __restrict__ gws,
                                                 const float* __restrict__ gph) {
    __shared__ float zre[2112], zim[2112];
    __shared__ float2 wt[682];
    const int t  = threadIdx.x;
    const int b  = blockIdx.x >> 10;
    const int cp = blockIdx.x & 1023;
    const int c0 = cp * 2;
    const size_t base0 = ((size_t)b * 2048 + c0) * 2048;
    const size_t base1 = base0 + 2048;

    for (int i = t; i < 682; i += 256) wt[i] = gws[i];

    float ph[4];
    float PH1r[4], PH1i[4], PH2r[4], PH2i[4];
    float ph24 = 0.f, PH24_1 = 0.f, PH24_2 = 0.f;

#pragma unroll
    for (int ch = 0; ch < 2; ++ch) {
        const size_t base = ch ? base1 : base0;
        const u16* Qp = Qt + base;
        const u16* Kp = Kt + base;
        __syncthreads();
#pragma unroll
        for (int u = 0; u < 8; ++u) {
            int s = t + u * 256;
            int r = __brev((unsigned)s) >> 21;
            zre[PD(r)] = bf2f(Qp[s]);
            zim[PD(r)] = bf2f(Kp[s]);
        }
        fft2048(zre, zim, wt, t);
        const float ac = alpha[c0 + ch];
#pragma unroll
        for (int u = 0; u < 4; ++u) {
            int k = t + u * 256;
            int m = (2048 - k) & 2047;
            float ar = zre[PD(k)], ai = zim[PD(k)];
            float br = zre[PD(m)], bi = zim[PD(m)];
            float qr = 0.5f * (ar + br), qi = 0.5f * (ai - bi);
            float kr = 0.5f * (ai + bi), ki = 0.5f * (br - ar);
            float cr = qr * kr + qi * ki;
            float ci = qi * kr - qr * ki;
            if (ch == 0) ph[u] = gph[min(k, 2048 - k)];
            float fr, fi;
            __sincosf(ph[u] * ac, &fi, &fr);
            float Pkr = cr * fr - ci * fi, Pki = cr * fi + ci * fr;
            float qr2 = 0.5f * (br + ar), qi2 = 0.5f * (bi - ai);
            float kr2 = 0.5f * (bi + ai), ki2 = 0.5f * (ar - br);
            float cr2 = qr2 * kr2 + qi2 * ki2;
            float ci2 = qi2 * kr2 - qr2 * ki2;
            float Pmr = cr2 * fr - ci2 * fi, Pmi = cr2 * fi + ci2 * fr;
            float hr = 0.5f * (Pkr + Pmr), hi = 0.5f * (Pki - Pmi);
            if (ch == 0) { PH1r[u] = hr; PH1i[u] = hi; }
            else         { PH2r[u] = hr; PH2i[u] = hi; }
        }
        if (t == 0) {
            float ar = zre[PD(1024)], ai = zim[PD(1024)];
            float cr = ar * ai;
            if (ch == 0) ph24 = gph[1024];
            float fr, fi;
            __sincosf(ph24 * ac, &fi, &fr);
            if (ch == 0) PH24_1 = cr * fr; else PH24_2 = cr * fr;
        }
    }

    __syncthreads();
#pragma unroll
    for (int u = 0; u < 4; ++u) {
        int k = t + u * 256;
        int m = (2048 - k) & 2047;
        int rk = __brev((unsigned)k) >> 21;
        int rm = __brev((unsigned)m) >> 21;
        zre[PD(rk)] = PH1r[u] - PH2i[u];
        zim[PD(rk)] = PH1i[u] + PH2r[u];
        zre[PD(rm)] = PH1r[u] + PH2i[u];
        zim[PD(rm)] = PH2r[u] - PH1i[u];
    }
    if (t == 0) {
        zre[PD(1)] = PH24_1;
        zim[PD(1)] = PH24_2;
    }
    fft2048(zre, zim, wt, t);

#pragma unroll
    for (int u = 0; u < 8; ++u) {
        int s = t + u * 256;
        int j = (2048 - s) & 2047;
        float w0 = zre[PD(j)] * (1.0f / 2048.0f);
        float w1 = zim[PD(j)] * (1.0f / 2048.0f);
        Vt[base0 + s] = f2bf(bf2f(Vt[base0 + s]) * w0);
        Vt[base1 + s] = f2bf(bf2f(Vt[base1 + s]) * w1);
    }
}

// ---------------------------------------------------------------------------
// Transpose [B][C][S] bf16 -> [(b,s)][c] bf16 (also used for 2048x2048, B=1)
// ---------------------------------------------------------------------------
__global__ __launch_bounds__(256) void transpose_k(const u16* __restrict__ in,
                                                   u16* __restrict__ out) {
    __shared__ u16 tile[32][33];
    int b = blockIdx.z;
    int c0 = blockIdx.x * 32, s0 = blockIdx.y * 32;
    int tx = threadIdx.x, ty = threadIdx.y;
#pragma unroll
    for (int dy = 0; dy < 32; dy += 8)
        tile[ty + dy][tx] = in[((size_t)b * 2048 + c0 + ty + dy) * 2048 + s0 + tx];
    __syncthreads();
#pragma unroll
    for (int dy = 0; dy < 32; dy += 8)
        out[((size_t)b * 2048 + s0 + ty + dy) * 2048 + c0 + tx] = tile[tx][ty + dy];
}

// ---------------------------------------------------------------------------
extern "C" void kernel_launch(void* const* d_in, const int* in_sizes, int n_in,
                              void* d_out, int out_size, void* d_ws, size_t ws_size,
                              hipStream_t stream) {
    const float* query = (const float*)d_in[0];
    const float* key   = (const float*)d_in[1];
    const float* value = (const float*)d_in[2];
    const float* Wq    = (const float*)d_in[3];
    const float* bq    = (const float*)d_in[4];
    const float* Wk    = (const float*)d_in[5];
    const float* bk    = (const float*)d_in[6];
    const float* Wv    = (const float*)d_in[7];
    const float* bv    = (const float*)d_in[8];
    const float* alpha = (const float*)d_in[9];
    const float* Wint  = (const float*)d_in[10];
    const float* bint  = (const float*)d_in[11];
    const float* Wfin  = (const float*)d_in[12];
    const float* bfin  = (const float*)d_in[13];
    const float* Wout  = (const float*)d_in[14];
    const float* bout  = (const float*)d_in[15];

    char* ws = (char*)d_ws;
    size_t off = 0;
    auto alloc = [&](size_t bytes) -> void* {
        void* p = ws + off;
        off += (bytes + 255) & ~(size_t)255;
        return p;
    };
    u16* Eq   = (u16*)alloc((size_t)2048 * 512 * 2);
    u16* Ek   = (u16*)alloc((size_t)2048 * 512 * 2);
    u16* Ev   = (u16*)alloc((size_t)2048 * 512 * 2);
    u16* Eint = (u16*)alloc((size_t)2048 * 2048 * 2);   // later reused as Ecomb
    u16* Efin = (u16*)alloc((size_t)2048 * 2048 * 2);
    u16* Eout = (u16*)alloc((size_t)2048 * 2048 * 2);
    u16* EintT= (u16*)alloc((size_t)2048 * 2048 * 2);
    u16* T1T  = (u16*)alloc((size_t)2048 * 2048 * 2);
    u16* Qt   = (u16*)alloc((size_t)4 * 2048 * 2048 * 2);  // [B][C][S]
    u16* Kt   = (u16*)alloc((size_t)4 * 2048 * 2048 * 2);
    u16* Vt   = (u16*)alloc((size_t)4 * 2048 * 2048 * 2);
    u16* attn = (u16*)alloc((size_t)8192 * 2048 * 2);
    float2* gws = (float2*)alloc(682 * 8);
    float*  pht = (float*)alloc(1025 * 4);
    float*  bv1 = (float*)alloc(2048 * 4);
    float*  bv2 = (float*)alloc(2048 * 4);
    u16* Ecomb = Eint;   // Eint's normal form is dead after EintT is built
    u16* Aq = attn;
    u16* Ak = attn + (size_t)8192 * 512;
    u16* Av = attn + (size_t)8192 * 1024;

    const int n8 = 8192 * 512 / 8;
    cvt_bf16<<<(n8 + 255) / 256, 256, 0, stream>>>(query, Aq, n8);
    cvt_bf16<<<(n8 + 255) / 256, 256, 0, stream>>>(key,   Ak, n8);
    cvt_bf16<<<(n8 + 255) / 256, 256, 0, stream>>>(value, Av, n8);

    build_tabs<<<5, 256, 0, stream>>>(gws, pht);

    build_E<<<(2048 * 512  + 255) / 256, 256, 0, stream>>>(Wq,   Eq,   9);
    build_E<<<(2048 * 512  + 255) / 256, 256, 0, stream>>>(Wk,   Ek,   9);
    build_E<<<(2048 * 512  + 255) / 256, 256, 0, stream>>>(Wv,   Ev,   9);
    build_E<<<(2048 * 2048 + 255) / 256, 256, 0, stream>>>(Wint, Eint, 11);
    build_E<<<(2048 * 2048 + 255) / 256, 256, 0, stream>>>(Wfin, Efin, 11);
    build_E<<<(2048 * 2048 + 255) / 256, 256, 0, stream>>>(Wout, Eout, 11);

    // ---- weight-chain collapse: Ecomb = Eout * Efin * Eint ----
    dim3 gt1(64, 64, 1);
    transpose_k<<<gt1, dim3(32, 8), 0, stream>>>(Eint, EintT);   // EintT[j][k]=Eint[k][j]
    // T1 = Efin*Eint, stored transposed (OUTMODE 2 with M=2048 -> [n][m])
    gemm2<2048, 2, 16><<<256, 256, 0, stream>>>(Efin, EintT, nullptr, T1T);
    // Ecomb = Eout*T1  (Earg[j][k]=T1[k][j]=T1T[j][k])
    gemm2<2048, 0, 16><<<256, 256, 0, stream>>>(Eout, T1T, nullptr, Ecomb);
    // combined bias: bv2 = (bint*Efin^T + bfin)*Eout^T + bout
    matvec_E<<<512, 256, 0, stream>>>(bint, Efin, bfin, bv1);
    matvec_E<<<512, 256, 0, stream>>>(bv1,  Eout, bout, bv2);

    const int g2 = 1024;   // data GEMMs: NBX=16, NBY=64
    gemm2<512, 2, 64><<<g2, 256, 0, stream>>>(Aq, Eq, bq, Qt);
    gemm2<512, 2, 64><<<g2, 256, 0, stream>>>(Ak, Ek, bk, Kt);
    gemm2<512, 2, 64><<<g2, 256, 0, stream>>>(Av, Ev, bv, Vt);

    spectral3<<<4096, 256, 0, stream>>>(Qt, Kt, Vt, alpha, gws, pht);

    dim3 gt(64, 64, 4);
    transpose_k<<<gt, dim3(32, 8), 0, stream>>>(Vt, attn);

    // single fused trailing linear
    gemm2<2048, 1, 64><<<g2, 256, 0, stream>>>(attn, Ecomb, bv2, (float*)d_out);
}

// Round 10
// 443.770 us; speedup vs baseline: 1.1408x; 1.0112x over previous
//
#include <hip/hip_runtime.h>
#include <hip/hip_bf16.h>
#include <cstdint>

typedef unsigned short u16;
typedef u16  u16x8 __attribute__((ext_vector_type(8)));
typedef short s16x8 __attribute__((ext_vector_type(8)));
typedef float f32x4 __attribute__((ext_vector_type(4)));

#define PI_F 3.14159265358979323846f
#define PD(i) ((i) + ((i) >> 5))

static __device__ __forceinline__ u16 f2bf(float f) {
    union { float f; unsigned u; } v; v.f = f;
    unsigned r = v.u + 0x7fffu + ((v.u >> 16) & 1u);
    return (u16)(r >> 16);
}
static __device__ __forceinline__ float bf2f(u16 h) {
    union { unsigned u; float f; } v; v.u = ((unsigned)h) << 16;
    return v.f;
}

__device__ __forceinline__ void gl_lds16(const u16* g, u16* l) {
    __builtin_amdgcn_global_load_lds(
        (const __attribute__((address_space(1))) unsigned int*)g,
        (__attribute__((address_space(3))) unsigned int*)l, 16, 0, 0);
}

// ---------------------------------------------------------------------------
// f32 -> bf16 convert (vectorized)
// ---------------------------------------------------------------------------
__global__ __launch_bounds__(256) void cvt_bf16(const float* __restrict__ in,
                                                u16* __restrict__ out, int n8) {
    int i = blockIdx.x * 256 + threadIdx.x;
    if (i >= n8) return;
    float4 a = ((const float4*)in)[2 * i];
    float4 b = ((const float4*)in)[2 * i + 1];
    u16x8 v;
    v[0] = f2bf(a.x); v[1] = f2bf(a.y); v[2] = f2bf(a.z); v[3] = f2bf(a.w);
    v[4] = f2bf(b.x); v[5] = f2bf(b.y); v[6] = f2bf(b.z); v[7] = f2bf(b.w);
    ((u16x8*)out)[i] = v;
}

// ---------------------------------------------------------------------------
// Expand quaternion weight W[4][512][in_q] into real matrix E[2048][4*in_q] bf16
// ---------------------------------------------------------------------------
__global__ void build_E(const float* __restrict__ W, u16* __restrict__ E, int logK) {
    const int K = 1 << logK;
    int idx = blockIdx.x * 256 + threadIdx.x;
    if (idx >= (2048 << logK)) return;
    int n = idx >> logK, k = idx & (K - 1);
    int o = n >> 2, c = n & 3, i = k >> 2, cp = k & 3;
    const int   qm[4][4] = {{0,1,2,3},{1,0,3,2},{2,3,0,1},{3,2,1,0}};
    const float qs[4][4] = {{1.f,-1.f,-1.f,-1.f},{1.f,1.f,1.f,-1.f},
                            {1.f,-1.f,1.f,1.f},{1.f,1.f,-1.f,1.f}};
    int in_q = K >> 2;
    float w = W[(size_t)qm[c][cp] * 512 * in_q + (size_t)o * in_q + i] * qs[c][cp];
    E[idx] = f2bf(w);
}

// ---------------------------------------------------------------------------
// Tables: per-pass twiddle sub-tables (contiguous, conflict-free) + phases.
// ---------------------------------------------------------------------------
__global__ __launch_bounds__(256) void build_tabs(float2* __restrict__ gws,
                                                  float* __restrict__ ph) {
    int i = blockIdx.x * 256 + threadIdx.x;
    if (i < 682) {
        int off, lh;
        if (i < 2)        { off = 0;   lh = 1; }
        else if (i < 10)  { off = 2;   lh = 3; }
        else if (i < 42)  { off = 10;  lh = 5; }
        else if (i < 170) { off = 42;  lh = 7; }
        else              { off = 170; lh = 9; }
        int j = i - off;
        float a = (-PI_F) * (float)j / (float)(2 << lh);
        gws[i] = make_float2(cosf(a), sinf(a));
    }
    if (i <= 1024) {
        ph[i] = atanf(logf((float)i * (1.0f / 2048.0f) + 1e-6f));
    }
}

// ---------------------------------------------------------------------------
// Bias matvec: out[n] = sum_k v[k]*E[n][k] + badd[n]   (one wave per n)
// ---------------------------------------------------------------------------
__global__ __launch_bounds__(256) void matvec_E(const float* __restrict__ v,
                                                const u16* __restrict__ E,
                                                const float* __restrict__ badd,
                                                float* __restrict__ out) {
    int n    = (blockIdx.x * 256 + threadIdx.x) >> 6;
    int lane = threadIdx.x & 63;
    if (n >= 2048) return;
    const u16* row = E + (size_t)n * 2048;
    float s = 0.f;
    for (int j = lane; j < 2048; j += 64) s += v[j] * bf2f(row[j]);
#pragma unroll
    for (int o = 32; o; o >>= 1) s += __shfl_down(s, o, 64);
    if (lane == 0) out[n] = s + badd[n];
}

// ---------------------------------------------------------------------------
// bf16 MFMA GEMM (m97 structure + generic XCD super-tiles).
// Grid = 1D, NBX=16 (N=2048), NBY template (M/128). nwg = 16*NBY.
// OUTMODE 0: bf16 [m][n]; 1: f32 [m][n]; 2: bf16 transposed [n][m] (/[b][n][s])
// bias may be nullptr.
// ---------------------------------------------------------------------------
template<int K, int OUTMODE, int NBY>
__global__ __launch_bounds__(256) void gemm2(const u16* __restrict__ A,
                                             const u16* __restrict__ E,
                                             const float* __restrict__ bias,
                                             void* __restrict__ outp) {
    __shared__ u16 As[128 * 64];
    __shared__ u16 Bs[128 * 64];
    const int t    = threadIdx.x;
    const int lane = t & 63, wave = t >> 6;
    const int wr   = wave >> 1, wc = wave & 1;
    const int lr   = lane & 15, kg = lane >> 4;
    const int l7   = lr & 7;

    // XCD-chunked 4x4 super-tile decode (8 XCDs, NBX=16)
    constexpr int SPX = (4 * (NBY / 4)) / 8;     // supertiles per XCD
    const int bid = blockIdx.x;
    const int xcd = bid & 7, p = bid >> 3;
    const int st  = xcd * SPX + (p >> 4);
    const int w   = p & 15;
    const int bx  = (st & 3) * 4 + (w & 3);
    const int by  = (st >> 2) * 4 + (w >> 2);
    const int m0  = by * 128;
    const int n0  = bx * 128;

    f32x4 acc[4][4];
#pragma unroll
    for (int i = 0; i < 4; ++i)
#pragma unroll
        for (int j = 0; j < 4; ++j) acc[i][j] = (f32x4){0.f, 0.f, 0.f, 0.f};

    const int arow = wr * 64 + lr;
    const int brow = wc * 64 + lr;

    for (int k0 = 0; k0 < K; k0 += 64) {
#pragma unroll
        for (int c = 0; c < 4; ++c) {
            int idx = t + c * 256;
            int row = idx >> 3, sl = idx & 7;
            int gsl = sl ^ (row & 7);
            gl_lds16(A + (size_t)(m0 + row) * K + k0 + gsl * 8, &As[idx * 8]);
            gl_lds16(E + (size_t)(n0 + row) * K + k0 + gsl * 8, &Bs[idx * 8]);
        }
        __syncthreads();
#pragma unroll
        for (int ks = 0; ks < 2; ++ks) {
            const int slot = (ks * 4 + kg) ^ l7;
            s16x8 av[4], bv[4];
#pragma unroll
            for (int mi = 0; mi < 4; ++mi)
                av[mi] = *(const s16x8*)&As[(arow + mi * 16) * 64 + slot * 8];
#pragma unroll
            for (int ni = 0; ni < 4; ++ni)
                bv[ni] = *(const s16x8*)&Bs[(brow + ni * 16) * 64 + slot * 8];
#pragma unroll
            for (int mi = 0; mi < 4; ++mi)
#pragma unroll
                for (int ni = 0; ni < 4; ++ni)
                    acc[mi][ni] = __builtin_amdgcn_mfma_f32_16x16x32_bf16(
                        av[mi], bv[ni], acc[mi][ni], 0, 0, 0);
        }
        __syncthreads();
    }

#pragma unroll
    for (int ni = 0; ni < 4; ++ni) {
        int n = n0 + wc * 64 + ni * 16 + lr;
        float bvl = bias ? bias[n] : 0.0f;
#pragma unroll
        for (int mi = 0; mi < 4; ++mi) {
#pragma unroll
            for (int r = 0; r < 4; ++r) {
                int m = m0 + wr * 64 + mi * 16 + kg * 4 + r;
                float val = acc[mi][ni][r] + bvl;
                if constexpr (OUTMODE == 0) {
                    ((u16*)outp)[(size_t)m * 2048 + n] = f2bf(val);
                } else if constexpr (OUTMODE == 1) {
                    ((float*)outp)[(size_t)m * 2048 + n] = val;
                } else {
                    int b = m >> 11, s = m & 2047;
                    ((u16*)outp)[((size_t)b * 2048 + n) * 2048 + s] = f2bf(val);
                }
            }
        }
    }
}

// ---------------------------------------------------------------------------
// In-place FFT, 2048 complex in padded LDS, bit-reversed input, natural
// output. Radix-2 (h=1, twiddle-free) + radix-4 passes lh=1,3,5,7,9.
// ---------------------------------------------------------------------------
template<int LH, int OFF>
__device__ __forceinline__ void r4pass(float* re, float* im,
                                       const float2* __restrict__ wt, int t) {
    constexpr int h = 1 << LH;
    __syncthreads();
#pragma unroll
    for (int u = 0; u < 2; ++u) {
        int vidx = t + u * 256;
        int j = vidx & (h - 1);
        int i0 = ((vidx >> LH) << (LH + 2)) | j;
        float2 w2 = wt[OFF + j];
        float w1r = w2.x * w2.x - w2.y * w2.y;
        float w1i = 2.f * w2.x * w2.y;
        float w3r = w2.y, w3i = -w2.x;
        int p0 = PD(i0), p1 = PD(i0 + h), p2 = PD(i0 + 2 * h), p3 = PD(i0 + 3 * h);
        float ar = re[p0], ai = im[p0];
        float br = re[p1], bi = im[p1];
        float cr = re[p2], ci = im[p2];
        float dr = re[p3], di = im[p3];
        float tbr = w1r * br - w1i * bi, tbi = w1r * bi + w1i * br;
        float tdr = w1r * dr - w1i * di, tdi = w1r * di + w1i * dr;
        float a1r = ar + tbr, a1i = ai + tbi;
        float b1r = ar - tbr, b1i = ai - tbi;
        float c1r = cr + tdr, c1i = ci + tdi;
        float d1r = cr - tdr, d1i = ci - tdi;
        float tcr = w2.x * c1r - w2.y * c1i, tci = w2.x * c1i + w2.y * c1r;
        float ter = w3r * d1r - w3i * d1i, tei = w3r * d1i + w3i * d1r;
        re[p0] = a1r + tcr; im[p0] = a1i + tci;
        re[p2] = a1r - tcr; im[p2] = a1i - tci;
        re[p1] = b1r + ter; im[p1] = b1i + tei;
        re[p3] = b1r - ter; im[p3] = b1i - tei;
    }
}

__device__ void fft2048(float* re, float* im, const float2* __restrict__ wt, int t) {
    __syncthreads();
#pragma unroll
    for (int u = 0; u < 4; ++u) {
        int i0 = 2 * (t + u * 256);
        int p0 = PD(i0), p1 = p0 + 1;
        float ar = re[p0], ai = im[p0];
        float br = re[p1], bi = im[p1];
        re[p0] = ar + br; im[p0] = ai + bi;
        re[p1] = ar - br; im[p1] = ai - bi;
    }
    r4pass<1, 0>(re, im, wt, t);
    r4pass<3, 2>(re, im, wt, t);
    r4pass<5, 10>(re, im, wt, t);
    r4pass<7, 42>(re, im, wt, t);
    r4pass<9, 170>(re, im, wt, t);
    __syncthreads();
}

// ---------------------------------------------------------------------------
// Spectral attention: 2 channels/block, Q+iK packed forward FFTs (2),
// Hermitian-packed inverse (1). Table twiddles/phases. Vt *= w in place.
// ---------------------------------------------------------------------------
__global__ __launch_bounds__(256) void spectral3(const u16* __restrict__ Qt,
                                                 const u16* __restrict__ Kt,
                                                 u16* __restrict__ Vt,
                                                 const float* __restrict__ alpha,
                                                 const float2* __restrict__ gws,
                                                 const float* __restrict__ gph) {
    __shared__ float zre[2112], zim[2112];
    __shared__ float2 wt[682];
    const int t  = threadIdx.x;
    const int b  = blockIdx.x >> 10;
    const int cp = blockIdx.x & 1023;
    const int c0 = cp * 2;
    const size_t base0 = ((size_t)b * 2048 + c0) * 2048;
    const size_t base1 = base0 + 2048;

    for (int i = t; i < 682; i += 256) wt[i] = gws[i];

    float ph[4];
    float PH1r[4], PH1i[4], PH2r[4], PH2i[4];
    float ph24 = 0.f, PH24_1 = 0.f, PH24_2 = 0.f;

#pragma unroll
    for (int ch = 0; ch < 2; ++ch) {
        const size_t base = ch ? base1 : base0;
        const u16* Qp = Qt + base;
        const u16* Kp = Kt + base;
        __syncthreads();
#pragma unroll
        for (int u = 0; u < 8; ++u) {
            int s = t + u * 256;
            int r = __brev((unsigned)s) >> 21;
            zre[PD(r)] = bf2f(Qp[s]);
            zim[PD(r)] = bf2f(Kp[s]);
        }
        fft2048(zre, zim, wt, t);
        const float ac = alpha[c0 + ch];
#pragma unroll
        for (int u = 0; u < 4; ++u) {
            int k = t + u * 256;
            int m = (2048 - k) & 2047;
            float ar = zre[PD(k)], ai = zim[PD(k)];
            float br = zre[PD(m)], bi = zim[PD(m)];
            float qr = 0.5f * (ar + br), qi = 0.5f * (ai - bi);
            float kr = 0.5f * (ai + bi), ki = 0.5f * (br - ar);
            float cr = qr * kr + qi * ki;
            float ci = qi * kr - qr * ki;
            if (ch == 0) ph[u] = gph[min(k, 2048 - k)];
            float fr, fi;
            __sincosf(ph[u] * ac, &fi, &fr);
            float Pkr = cr * fr - ci * fi, Pki = cr * fi + ci * fr;
            float qr2 = 0.5f * (br + ar), qi2 = 0.5f * (bi - ai);
            float kr2 = 0.5f * (bi + ai), ki2 = 0.5f * (ar - br);
            float cr2 = qr2 * kr2 + qi2 * ki2;
            float ci2 = qi2 * kr2 - qr2 * ki2;
            float Pmr = cr2 * fr - ci2 * fi, Pmi = cr2 * fi + ci2 * fr;
            float hr = 0.5f * (Pkr + Pmr), hi = 0.5f * (Pki - Pmi);
            if (ch == 0) { PH1r[u] = hr; PH1i[u] = hi; }
            else         { PH2r[u] = hr; PH2i[u] = hi; }
        }
        if (t == 0) {
            float ar = zre[PD(1024)], ai = zim[PD(1024)];
            float cr = ar * ai;
            if (ch == 0) ph24 = gph[1024];
            float fr, fi;
            __sincosf(ph24 * ac, &fi, &fr);
            if (ch == 0) PH24_1 = cr * fr; else PH24_2 = cr * fr;
        }
    }

    __syncthreads();
#pragma unroll
    for (int u = 0; u < 4; ++u) {
        int k = t + u * 256;
        int m = (2048 - k) & 2047;
        int rk = __brev((unsigned)k) >> 21;
        int rm = __brev((unsigned)m) >> 21;
        zre[PD(rk)] = PH1r[u] - PH2i[u];
        zim[PD(rk)] = PH1i[u] + PH2r[u];
        zre[PD(rm)] = PH1r[u] + PH2i[u];
        zim[PD(rm)] = PH2r[u] - PH1i[u];
    }
    if (t == 0) {
        zre[PD(1)] = PH24_1;
        zim[PD(1)] = PH24_2;
    }
    fft2048(zre, zim, wt, t);

#pragma unroll
    for (int u = 0; u < 8; ++u) {
        int s = t + u * 256;
        int j = (2048 - s) & 2047;
        float w0 = zre[PD(j)] * (1.0f / 2048.0f);
        float w1 = zim[PD(j)] * (1.0f / 2048.0f);
        Vt[base0 + s] = f2bf(bf2f(Vt[base0 + s]) * w0);
        Vt[base1 + s] = f2bf(bf2f(Vt[base1 + s]) * w1);
    }
}

// ---------------------------------------------------------------------------
// Transpose [B][C][S] bf16 -> [(b,s)][c] bf16 (also used for 2048x2048, B=1)
// ---------------------------------------------------------------------------
__global__ __launch_bounds__(256) void transpose_k(const u16* __restrict__ in,
                                                   u16* __restrict__ out) {
    __shared__ u16 tile[32][33];
    int b = blockIdx.z;
    int c0 = blockIdx.x * 32, s0 = blockIdx.y * 32;
    int tx = threadIdx.x, ty = threadIdx.y;
#pragma unroll
    for (int dy = 0; dy < 32; dy += 8)
        tile[ty + dy][tx] = in[((size_t)b * 2048 + c0 + ty + dy) * 2048 + s0 + tx];
    __syncthreads();
#pragma unroll
    for (int dy = 0; dy < 32; dy += 8)
        out[((size_t)b * 2048 + s0 + ty + dy) * 2048 + c0 + tx] = tile[tx][ty + dy];
}

// ---------------------------------------------------------------------------
extern "C" void kernel_launch(void* const* d_in, const int* in_sizes, int n_in,
                              void* d_out, int out_size, void* d_ws, size_t ws_size,
                              hipStream_t stream) {
    const float* query = (const float*)d_in[0];
    const float* key   = (const float*)d_in[1];
    const float* value = (const float*)d_in[2];
    const float* Wq    = (const float*)d_in[3];
    const float* bq    = (const float*)d_in[4];
    const float* Wk    = (const float*)d_in[5];
    const float* bk    = (const float*)d_in[6];
    const float* Wv    = (const float*)d_in[7];
    const float* bv    = (const float*)d_in[8];
    const float* alpha = (const float*)d_in[9];
    const float* Wint  = (const float*)d_in[10];
    const float* bint  = (const float*)d_in[11];
    const float* Wfin  = (const float*)d_in[12];
    const float* bfin  = (const float*)d_in[13];
    const float* Wout  = (const float*)d_in[14];
    const float* bout  = (const float*)d_in[15];

    char* ws = (char*)d_ws;
    size_t off = 0;
    auto alloc = [&](size_t bytes) -> void* {
        void* p = ws + off;
        off += (bytes + 255) & ~(size_t)255;
        return p;
    };
    u16* Eq   = (u16*)alloc((size_t)2048 * 512 * 2);
    u16* Ek   = (u16*)alloc((size_t)2048 * 512 * 2);
    u16* Ev   = (u16*)alloc((size_t)2048 * 512 * 2);
    u16* Eint = (u16*)alloc((size_t)2048 * 2048 * 2);   // later reused as Ecomb
    u16* Efin = (u16*)alloc((size_t)2048 * 2048 * 2);
    u16* Eout = (u16*)alloc((size_t)2048 * 2048 * 2);
    u16* EintT= (u16*)alloc((size_t)2048 * 2048 * 2);
    u16* T1T  = (u16*)alloc((size_t)2048 * 2048 * 2);
    u16* Qt   = (u16*)alloc((size_t)4 * 2048 * 2048 * 2);  // [B][C][S]
    u16* Kt   = (u16*)alloc((size_t)4 * 2048 * 2048 * 2);
    u16* Vt   = (u16*)alloc((size_t)4 * 2048 * 2048 * 2);
    u16* attn = (u16*)alloc((size_t)8192 * 2048 * 2);
    float2* gws = (float2*)alloc(682 * 8);
    float*  pht = (float*)alloc(1025 * 4);
    float*  bv1 = (float*)alloc(2048 * 4);
    float*  bv2 = (float*)alloc(2048 * 4);
    u16* Ecomb = Eint;   // Eint's normal form is dead after EintT is built
    u16* Aq = attn;
    u16* Ak = attn + (size_t)8192 * 512;
    u16* Av = attn + (size_t)8192 * 1024;

    const int n8 = 8192 * 512 / 8;
    cvt_bf16<<<(n8 + 255) / 256, 256, 0, stream>>>(query, Aq, n8);
    cvt_bf16<<<(n8 + 255) / 256, 256, 0, stream>>>(key,   Ak, n8);
    cvt_bf16<<<(n8 + 255) / 256, 256, 0, stream>>>(value, Av, n8);

    build_tabs<<<5, 256, 0, stream>>>(gws, pht);

    build_E<<<(2048 * 512  + 255) / 256, 256, 0, stream>>>(Wq,   Eq,   9);
    build_E<<<(2048 * 512  + 255) / 256, 256, 0, stream>>>(Wk,   Ek,   9);
    build_E<<<(2048 * 512  + 255) / 256, 256, 0, stream>>>(Wv,   Ev,   9);
    build_E<<<(2048 * 2048 + 255) / 256, 256, 0, stream>>>(Wint, Eint, 11);
    build_E<<<(2048 * 2048 + 255) / 256, 256, 0, stream>>>(Wfin, Efin, 11);
    build_E<<<(2048 * 2048 + 255) / 256, 256, 0, stream>>>(Wout, Eout, 11);

    // ---- weight-chain collapse: Ecomb = Eout * Efin * Eint ----
    dim3 gt1(64, 64, 1);
    transpose_k<<<gt1, dim3(32, 8), 0, stream>>>(Eint, EintT);   // EintT[j][k]=Eint[k][j]
    // T1 = Efin*Eint, stored transposed (OUTMODE 2 with M=2048 -> [n][m])
    gemm2<2048, 2, 16><<<256, 256, 0, stream>>>(Efin, EintT, nullptr, T1T);
    // Ecomb = Eout*T1  (Earg[j][k]=T1[k][j]=T1T[j][k])
    gemm2<2048, 0, 16><<<256, 256, 0, stream>>>(Eout, T1T, nullptr, Ecomb);
    // combined bias: bv2 = (bint*Efin^T + bfin)*Eout^T + bout
    matvec_E<<<512, 256, 0, stream>>>(bint, Efin, bfin, bv1);
    matvec_E<<<512, 256, 0, stream>>>(bv1,  Eout, bout, bv2);

    const int g2 = 1024;   // data GEMMs: NBX=16, NBY=64
    gemm2<512, 2, 64><<<g2, 256, 0, stream>>>(Aq, Eq, bq, Qt);
    gemm2<512, 2, 64><<<g2, 256, 0, stream>>>(Ak, Ek, bk, Kt);
    gemm2<512, 2, 64><<<g2, 256, 0, stream>>>(Av, Ev, bv, Vt);

    spectral3<<<4096, 256, 0, stream>>>(Qt, Kt, Vt, alpha, gws, pht);

    dim3 gt(64, 64, 4);
    transpose_k<<<gt, dim3(32, 8), 0, stream>>>(Vt, attn);

    // single fused trailing linear
    gemm2<2048, 1, 64><<<g2, 256, 0, stream>>>(attn, Ecomb, bv2, (float*)d_out);
}

// Round 11
// 398.799 us; speedup vs baseline: 1.2695x; 1.1128x over previous
//
#include <hip/hip_runtime.h>
#include <hip/hip_bf16.h>
#include <cstdint>

typedef unsigned short u16;
typedef u16  u16x8 __attribute__((ext_vector_type(8)));
typedef short s16x8 __attribute__((ext_vector_type(8)));
typedef float f32x4 __attribute__((ext_vector_type(4)));

#define PI_F 3.14159265358979323846f
// padding: bank(3b+c) patterns are <=3-way for all FFT access modes
#define PD(i) ((i) + 3 * ((i) >> 5))

static __device__ __forceinline__ u16 f2bf(float f) {
    union { float f; unsigned u; } v; v.f = f;
    unsigned r = v.u + 0x7fffu + ((v.u >> 16) & 1u);
    return (u16)(r >> 16);
}
static __device__ __forceinline__ float bf2f(u16 h) {
    union { unsigned u; float f; } v; v.u = ((unsigned)h) << 16;
    return v.f;
}

__device__ __forceinline__ void gl_lds16(const u16* g, u16* l) {
    __builtin_amdgcn_global_load_lds(
        (const __attribute__((address_space(1))) unsigned int*)g,
        (__attribute__((address_space(3))) unsigned int*)l, 16, 0, 0);
}

// ---------------------------------------------------------------------------
// f32 -> bf16 convert (vectorized)
// ---------------------------------------------------------------------------
__global__ __launch_bounds__(256) void cvt_bf16(const float* __restrict__ in,
                                                u16* __restrict__ out, int n8) {
    int i = blockIdx.x * 256 + threadIdx.x;
    if (i >= n8) return;
    float4 a = ((const float4*)in)[2 * i];
    float4 b = ((const float4*)in)[2 * i + 1];
    u16x8 v;
    v[0] = f2bf(a.x); v[1] = f2bf(a.y); v[2] = f2bf(a.z); v[3] = f2bf(a.w);
    v[4] = f2bf(b.x); v[5] = f2bf(b.y); v[6] = f2bf(b.z); v[7] = f2bf(b.w);
    ((u16x8*)out)[i] = v;
}

// ---------------------------------------------------------------------------
// Expand quaternion weight W[4][512][in_q] into real matrix E[2048][4*in_q] bf16
// ---------------------------------------------------------------------------
__global__ void build_E(const float* __restrict__ W, u16* __restrict__ E, int logK) {
    const int K = 1 << logK;
    int idx = blockIdx.x * 256 + threadIdx.x;
    if (idx >= (2048 << logK)) return;
    int n = idx >> logK, k = idx & (K - 1);
    int o = n >> 2, c = n & 3, i = k >> 2, cp = k & 3;
    const int   qm[4][4] = {{0,1,2,3},{1,0,3,2},{2,3,0,1},{3,2,1,0}};
    const float qs[4][4] = {{1.f,-1.f,-1.f,-1.f},{1.f,1.f,1.f,-1.f},
                            {1.f,-1.f,1.f,1.f},{1.f,1.f,-1.f,1.f}};
    int in_q = K >> 2;
    float w = W[(size_t)qm[c][cp] * 512 * in_q + (size_t)o * in_q + i] * qs[c][cp];
    E[idx] = f2bf(w);
}

// ---------------------------------------------------------------------------
// Tables: per-pass twiddle sub-tables (contiguous, conflict-free) + phases.
// ---------------------------------------------------------------------------
__global__ __launch_bounds__(256) void build_tabs(float2* __restrict__ gws,
                                                  float* __restrict__ ph) {
    int i = blockIdx.x * 256 + threadIdx.x;
    if (i < 682) {
        int off, lh;
        if (i < 2)        { off = 0;   lh = 1; }
        else if (i < 10)  { off = 2;   lh = 3; }
        else if (i < 42)  { off = 10;  lh = 5; }
        else if (i < 170) { off = 42;  lh = 7; }
        else              { off = 170; lh = 9; }
        int j = i - off;
        float a = (-PI_F) * (float)j / (float)(2 << lh);
        gws[i] = make_float2(cosf(a), sinf(a));
    }
    if (i <= 1024) {
        ph[i] = atanf(logf((float)i * (1.0f / 2048.0f) + 1e-6f));
    }
}

// ---------------------------------------------------------------------------
// Bias matvec: out[n] = sum_k v[k]*E[n][k] + badd[n]   (one wave per n)
// ---------------------------------------------------------------------------
__global__ __launch_bounds__(256) void matvec_E(const float* __restrict__ v,
                                                const u16* __restrict__ E,
                                                const float* __restrict__ badd,
                                                float* __restrict__ out) {
    int n    = (blockIdx.x * 256 + threadIdx.x) >> 6;
    int lane = threadIdx.x & 63;
    if (n >= 2048) return;
    const u16* row = E + (size_t)n * 2048;
    float s = 0.f;
    for (int j = lane; j < 2048; j += 64) s += v[j] * bf2f(row[j]);
#pragma unroll
    for (int o = 32; o; o >>= 1) s += __shfl_down(s, o, 64);
    if (lane == 0) out[n] = s + badd[n];
}

// ---------------------------------------------------------------------------
// bf16 MFMA GEMM body (m97 structure + generic XCD super-tiles).
// NBX=16 (N=2048), NBY = M/128. Shared arrays passed in (one alloc/kernel).
// OUTMODE 0: bf16 [m][n]; 1: f32 [m][n]; 2: bf16 transposed [n][m]/[b][n][s]
// ---------------------------------------------------------------------------
template<int K, int OUTMODE, int NBY>
__device__ __forceinline__ void gemm_body(int bid, u16* As, u16* Bs,
                                          const u16* __restrict__ A,
                                          const u16* __restrict__ E,
                                          const float* __restrict__ bias,
                                          void* __restrict__ outp) {
    const int t    = threadIdx.x;
    const int lane = t & 63, wave = t >> 6;
    const int wr   = wave >> 1, wc = wave & 1;
    const int lr   = lane & 15, kg = lane >> 4;
    const int l7   = lr & 7;

    // XCD-chunked 4x4 super-tile decode (8 XCDs, NBX=16)
    constexpr int SPX = (4 * (NBY / 4)) / 8;     // supertiles per XCD
    const int xcd = bid & 7, p = bid >> 3;
    const int st  = xcd * SPX + (p >> 4);
    const int w   = p & 15;
    const int bx  = (st & 3) * 4 + (w & 3);
    const int by  = (st >> 2) * 4 + (w >> 2);
    const int m0  = by * 128;
    const int n0  = bx * 128;

    f32x4 acc[4][4];
#pragma unroll
    for (int i = 0; i < 4; ++i)
#pragma unroll
        for (int j = 0; j < 4; ++j) acc[i][j] = (f32x4){0.f, 0.f, 0.f, 0.f};

    const int arow = wr * 64 + lr;
    const int brow = wc * 64 + lr;

    for (int k0 = 0; k0 < K; k0 += 64) {
#pragma unroll
        for (int c = 0; c < 4; ++c) {
            int idx = t + c * 256;
            int row = idx >> 3, sl = idx & 7;
            int gsl = sl ^ (row & 7);
            gl_lds16(A + (size_t)(m0 + row) * K + k0 + gsl * 8, &As[idx * 8]);
            gl_lds16(E + (size_t)(n0 + row) * K + k0 + gsl * 8, &Bs[idx * 8]);
        }
        __syncthreads();
#pragma unroll
        for (int ks = 0; ks < 2; ++ks) {
            const int slot = (ks * 4 + kg) ^ l7;
            s16x8 av[4], bv[4];
#pragma unroll
            for (int mi = 0; mi < 4; ++mi)
                av[mi] = *(const s16x8*)&As[(arow + mi * 16) * 64 + slot * 8];
#pragma unroll
            for (int ni = 0; ni < 4; ++ni)
                bv[ni] = *(const s16x8*)&Bs[(brow + ni * 16) * 64 + slot * 8];
#pragma unroll
            for (int mi = 0; mi < 4; ++mi)
#pragma unroll
                for (int ni = 0; ni < 4; ++ni)
                    acc[mi][ni] = __builtin_amdgcn_mfma_f32_16x16x32_bf16(
                        av[mi], bv[ni], acc[mi][ni], 0, 0, 0);
        }
        __syncthreads();
    }

#pragma unroll
    for (int ni = 0; ni < 4; ++ni) {
        int n = n0 + wc * 64 + ni * 16 + lr;
        float bvl = bias ? bias[n] : 0.0f;
#pragma unroll
        for (int mi = 0; mi < 4; ++mi) {
#pragma unroll
            for (int r = 0; r < 4; ++r) {
                int m = m0 + wr * 64 + mi * 16 + kg * 4 + r;
                float val = acc[mi][ni][r] + bvl;
                if constexpr (OUTMODE == 0) {
                    ((u16*)outp)[(size_t)m * 2048 + n] = f2bf(val);
                } else if constexpr (OUTMODE == 1) {
                    ((float*)outp)[(size_t)m * 2048 + n] = val;
                } else {
                    int b = m >> 11, s = m & 2047;
                    ((u16*)outp)[((size_t)b * 2048 + n) * 2048 + s] = f2bf(val);
                }
            }
        }
    }
}

template<int K, int OUTMODE, int NBY>
__global__ __launch_bounds__(256) void gemm2(const u16* __restrict__ A,
                                             const u16* __restrict__ E,
                                             const float* __restrict__ bias,
                                             void* __restrict__ outp) {
    __shared__ u16 As[128 * 64];
    __shared__ u16 Bs[128 * 64];
    gemm_body<K, OUTMODE, NBY>(blockIdx.x, As, Bs, A, E, bias, outp);
}

// Fat kernel 1: combine1 (Efin*EintT -> T1T, 256 blocks, first) + projQ (1024)
__global__ __launch_bounds__(256) void gemm_fat1(const u16* __restrict__ Aq,
                                                 const u16* __restrict__ Eq,
                                                 const float* __restrict__ bq,
                                                 void* __restrict__ Qt,
                                                 const u16* __restrict__ Efin,
                                                 const u16* __restrict__ EintT,
                                                 void* __restrict__ T1T) {
    __shared__ u16 As[128 * 64];
    __shared__ u16 Bs[128 * 64];
    int bid = blockIdx.x;
    if (bid < 256)
        gemm_body<2048, 2, 16>(bid, As, Bs, Efin, EintT, nullptr, T1T);
    else
        gemm_body<512, 2, 64>(bid - 256, As, Bs, Aq, Eq, bq, Qt);
}

// Fat kernel 2: combine2 (Eout*T1T -> Ecomb, 256 blocks, first) + projK (1024)
__global__ __launch_bounds__(256) void gemm_fat2(const u16* __restrict__ Ak,
                                                 const u16* __restrict__ Ek,
                                                 const float* __restrict__ bk,
                                                 void* __restrict__ Kt,
                                                 const u16* __restrict__ Eout,
                                                 const u16* __restrict__ T1T,
                                                 void* __restrict__ Ecomb) {
    __shared__ u16 As[128 * 64];
    __shared__ u16 Bs[128 * 64];
    int bid = blockIdx.x;
    if (bid < 256)
        gemm_body<2048, 0, 16>(bid, As, Bs, Eout, T1T, nullptr, Ecomb);
    else
        gemm_body<512, 2, 64>(bid - 256, As, Bs, Ak, Ek, bk, Kt);
}

// ---------------------------------------------------------------------------
// In-place FFT, 2048 complex in padded LDS, bit-reversed input, natural
// output. Radix-2 (h=1, twiddle-free) + radix-4 passes lh=1,3,5,7,9.
// ---------------------------------------------------------------------------
template<int LH, int OFF>
__device__ __forceinline__ void r4pass(float* re, float* im,
                                       const float2* __restrict__ wt, int t) {
    constexpr int h = 1 << LH;
    __syncthreads();
#pragma unroll
    for (int u = 0; u < 2; ++u) {
        int vidx = t + u * 256;
        int j = vidx & (h - 1);
        int i0 = ((vidx >> LH) << (LH + 2)) | j;
        float2 w2 = wt[OFF + j];
        float w1r = w2.x * w2.x - w2.y * w2.y;
        float w1i = 2.f * w2.x * w2.y;
        float w3r = w2.y, w3i = -w2.x;
        int p0 = PD(i0), p1 = PD(i0 + h), p2 = PD(i0 + 2 * h), p3 = PD(i0 + 3 * h);
        float ar = re[p0], ai = im[p0];
        float br = re[p1], bi = im[p1];
        float cr = re[p2], ci = im[p2];
        float dr = re[p3], di = im[p3];
        float tbr = w1r * br - w1i * bi, tbi = w1r * bi + w1i * br;
        float tdr = w1r * dr - w1i * di, tdi = w1r * di + w1i * dr;
        float a1r = ar + tbr, a1i = ai + tbi;
        float b1r = ar - tbr, b1i = ai - tbi;
        float c1r = cr + tdr, c1i = ci + tdi;
        float d1r = cr - tdr, d1i = ci - tdi;
        float tcr = w2.x * c1r - w2.y * c1i, tci = w2.x * c1i + w2.y * c1r;
        float ter = w3r * d1r - w3i * d1i, tei = w3r * d1i + w3i * d1r;
        re[p0] = a1r + tcr; im[p0] = a1i + tci;
        re[p2] = a1r - tcr; im[p2] = a1i - tci;
        re[p1] = b1r + ter; im[p1] = b1i + tei;
        re[p3] = b1r - ter; im[p3] = b1i - tei;
    }
}

__device__ void fft2048(float* re, float* im, const float2* __restrict__ wt, int t) {
    __syncthreads();
#pragma unroll
    for (int u = 0; u < 4; ++u) {
        int i0 = 2 * (t + u * 256);
        int p0 = PD(i0), p1 = p0 + 1;   // i0 even, i0%32 != 31 -> PD(i0+1)=PD(i0)+1
        float ar = re[p0], ai = im[p0];
        float br = re[p1], bi = im[p1];
        re[p0] = ar + br; im[p0] = ai + bi;
        re[p1] = ar - br; im[p1] = ai - bi;
    }
    r4pass<1, 0>(re, im, wt, t);
    r4pass<3, 2>(re, im, wt, t);
    r4pass<5, 10>(re, im, wt, t);
    r4pass<7, 42>(re, im, wt, t);
    r4pass<9, 170>(re, im, wt, t);
    __syncthreads();
}

// ---------------------------------------------------------------------------
// Spectral attention: 2 channels/block, Q+iK packed forward FFTs (2),
// Hermitian-packed inverse (1). Table twiddles/phases. Vt *= w in place.
// ---------------------------------------------------------------------------
__global__ __launch_bounds__(256) void spectral3(const u16* __restrict__ Qt,
                                                 const u16* __restrict__ Kt,
                                                 u16* __restrict__ Vt,
                                                 const float* __restrict__ alpha,
                                                 const float2* __restrict__ gws,
                                                 const float* __restrict__ gph) {
    __shared__ float zre[2240], zim[2240];
    __shared__ float2 wt[682];
    const int t  = threadIdx.x;
    const int b  = blockIdx.x >> 10;
    const int cp = blockIdx.x & 1023;
    const int c0 = cp * 2;
    const size_t base0 = ((size_t)b * 2048 + c0) * 2048;
    const size_t base1 = base0 + 2048;

    for (int i = t; i < 682; i += 256) wt[i] = gws[i];

    float ph[4];
    float PH1r[4], PH1i[4], PH2r[4], PH2i[4];
    float ph24 = 0.f, PH24_1 = 0.f, PH24_2 = 0.f;

#pragma unroll
    for (int ch = 0; ch < 2; ++ch) {
        const size_t base = ch ? base1 : base0;
        const u16* Qp = Qt + base;
        const u16* Kp = Kt + base;
        __syncthreads();
#pragma unroll
        for (int u = 0; u < 8; ++u) {
            int s = t + u * 256;
            int r = __brev((unsigned)s) >> 21;
            zre[PD(r)] = bf2f(Qp[s]);
            zim[PD(r)] = bf2f(Kp[s]);
        }
        fft2048(zre, zim, wt, t);
        const float ac = alpha[c0 + ch];
#pragma unroll
        for (int u = 0; u < 4; ++u) {
            int k = t + u * 256;
            int m = (2048 - k) & 2047;
            float ar = zre[PD(k)], ai = zim[PD(k)];
            float br = zre[PD(m)], bi = zim[PD(m)];
            float qr = 0.5f * (ar + br), qi = 0.5f * (ai - bi);
            float kr = 0.5f * (ai + bi), ki = 0.5f * (br - ar);
            float cr = qr * kr + qi * ki;
            float ci = qi * kr - qr * ki;
            if (ch == 0) ph[u] = gph[min(k, 2048 - k)];
            float fr, fi;
            __sincosf(ph[u] * ac, &fi, &fr);
            float Pkr = cr * fr - ci * fi, Pki = cr * fi + ci * fr;
            float qr2 = 0.5f * (br + ar), qi2 = 0.5f * (bi - ai);
            float kr2 = 0.5f * (bi + ai), ki2 = 0.5f * (ar - br);
            float cr2 = qr2 * kr2 + qi2 * ki2;
            float ci2 = qi2 * kr2 - qr2 * ki2;
            float Pmr = cr2 * fr - ci2 * fi, Pmi = cr2 * fi + ci2 * fr;
            float hr = 0.5f * (Pkr + Pmr), hi = 0.5f * (Pki - Pmi);
            if (ch == 0) { PH1r[u] = hr; PH1i[u] = hi; }
            else         { PH2r[u] = hr; PH2i[u] = hi; }
        }
        if (t == 0) {
            float ar = zre[PD(1024)], ai = zim[PD(1024)];
            float cr = ar * ai;
            if (ch == 0) ph24 = gph[1024];
            float fr, fi;
            __sincosf(ph24 * ac, &fi, &fr);
            if (ch == 0) PH24_1 = cr * fr; else PH24_2 = cr * fr;
        }
    }

    __syncthreads();
#pragma unroll
    for (int u = 0; u < 4; ++u) {
        int k = t + u * 256;
        int m = (2048 - k) & 2047;
        int rk = __brev((unsigned)k) >> 21;
        int rm = __brev((unsigned)m) >> 21;
        zre[PD(rk)] = PH1r[u] - PH2i[u];
        zim[PD(rk)] = PH1i[u] + PH2r[u];
        zre[PD(rm)] = PH1r[u] + PH2i[u];
        zim[PD(rm)] = PH2r[u] - PH1i[u];
    }
    if (t == 0) {
        zre[PD(1)] = PH24_1;
        zim[PD(1)] = PH24_2;
    }
    fft2048(zre, zim, wt, t);

#pragma unroll
    for (int u = 0; u < 8; ++u) {
        int s = t + u * 256;
        int j = (2048 - s) & 2047;
        float w0 = zre[PD(j)] * (1.0f / 2048.0f);
        float w1 = zim[PD(j)] * (1.0f / 2048.0f);
        Vt[base0 + s] = f2bf(bf2f(Vt[base0 + s]) * w0);
        Vt[base1 + s] = f2bf(bf2f(Vt[base1 + s]) * w1);
    }
}

// ---------------------------------------------------------------------------
// Transpose [B][C][S] bf16 -> [(b,s)][c] bf16 (also used for 2048x2048, B=1)
// ---------------------------------------------------------------------------
__global__ __launch_bounds__(256) void transpose_k(const u16* __restrict__ in,
                                                   u16* __restrict__ out) {
    __shared__ u16 tile[32][33];
    int b = blockIdx.z;
    int c0 = blockIdx.x * 32, s0 = blockIdx.y * 32;
    int tx = threadIdx.x, ty = threadIdx.y;
#pragma unroll
    for (int dy = 0; dy < 32; dy += 8)
        tile[ty + dy][tx] = in[((size_t)b * 2048 + c0 + ty + dy) * 2048 + s0 + tx];
    __syncthreads();
#pragma unroll
    for (int dy = 0; dy < 32; dy += 8)
        out[((size_t)b * 2048 + s0 + ty + dy) * 2048 + c0 + tx] = tile[tx][ty + dy];
}

// ---------------------------------------------------------------------------
extern "C" void kernel_launch(void* const* d_in, const int* in_sizes, int n_in,
                              void* d_out, int out_size, void* d_ws, size_t ws_size,
                              hipStream_t stream) {
    const float* query = (const float*)d_in[0];
    const float* key   = (const float*)d_in[1];
    const float* value = (const float*)d_in[2];
    const float* Wq    = (const float*)d_in[3];
    const float* bq    = (const float*)d_in[4];
    const float* Wk    = (const float*)d_in[5];
    const float* bk    = (const float*)d_in[6];
    const float* Wv    = (const float*)d_in[7];
    const float* bv    = (const float*)d_in[8];
    const float* alpha = (const float*)d_in[9];
    const float* Wint  = (const float*)d_in[10];
    const float* bint  = (const float*)d_in[11];
    const float* Wfin  = (const float*)d_in[12];
    const float* bfin  = (const float*)d_in[13];
    const float* Wout  = (const float*)d_in[14];
    const float* bout  = (const float*)d_in[15];

    char* ws = (char*)d_ws;
    size_t off = 0;
    auto alloc = [&](size_t bytes) -> void* {
        void* p = ws + off;
        off += (bytes + 255) & ~(size_t)255;
        return p;
    };
    u16* Eq   = (u16*)alloc((size_t)2048 * 512 * 2);
    u16* Ek   = (u16*)alloc((size_t)2048 * 512 * 2);
    u16* Ev   = (u16*)alloc((size_t)2048 * 512 * 2);
    u16* Eint = (u16*)alloc((size_t)2048 * 2048 * 2);   // later reused as Ecomb
    u16* Efin = (u16*)alloc((size_t)2048 * 2048 * 2);
    u16* Eout = (u16*)alloc((size_t)2048 * 2048 * 2);
    u16* EintT= (u16*)alloc((size_t)2048 * 2048 * 2);
    u16* T1T  = (u16*)alloc((size_t)2048 * 2048 * 2);
    u16* Qt   = (u16*)alloc((size_t)4 * 2048 * 2048 * 2);  // [B][C][S]
    u16* Kt   = (u16*)alloc((size_t)4 * 2048 * 2048 * 2);
    u16* Vt   = (u16*)alloc((size_t)4 * 2048 * 2048 * 2);
    u16* attn = (u16*)alloc((size_t)8192 * 2048 * 2);
    float2* gws = (float2*)alloc(682 * 8);
    float*  pht = (float*)alloc(1025 * 4);
    float*  bv1 = (float*)alloc(2048 * 4);
    float*  bv2 = (float*)alloc(2048 * 4);
    u16* Ecomb = Eint;   // Eint's normal form is dead once EintT exists
    u16* Aq = attn;
    u16* Ak = attn + (size_t)8192 * 512;
    u16* Av = attn + (size_t)8192 * 1024;

    const int n8 = 8192 * 512 / 8;
    cvt_bf16<<<(n8 + 255) / 256, 256, 0, stream>>>(query, Aq, n8);
    cvt_bf16<<<(n8 + 255) / 256, 256, 0, stream>>>(key,   Ak, n8);
    cvt_bf16<<<(n8 + 255) / 256, 256, 0, stream>>>(value, Av, n8);

    build_tabs<<<5, 256, 0, stream>>>(gws, pht);

    build_E<<<(2048 * 512  + 255) / 256, 256, 0, stream>>>(Wq,   Eq,   9);
    build_E<<<(2048 * 512  + 255) / 256, 256, 0, stream>>>(Wk,   Ek,   9);
    build_E<<<(2048 * 512  + 255) / 256, 256, 0, stream>>>(Wv,   Ev,   9);
    build_E<<<(2048 * 2048 + 255) / 256, 256, 0, stream>>>(Wint, Eint, 11);
    build_E<<<(2048 * 2048 + 255) / 256, 256, 0, stream>>>(Wfin, Efin, 11);
    build_E<<<(2048 * 2048 + 255) / 256, 256, 0, stream>>>(Wout, Eout, 11);

    // EintT[j][k] = Eint[k][j]
    dim3 gt1(64, 64, 1);
    transpose_k<<<gt1, dim3(32, 8), 0, stream>>>(Eint, EintT);

    // fat1: combine1 (T1 = Efin*Eint, stored T1T) co-scheduled with projQ
    gemm_fat1<<<1280, 256, 0, stream>>>(Aq, Eq, bq, Qt, Efin, EintT, T1T);
    // fat2: combine2 (Ecomb = Eout*T1) co-scheduled with projK
    gemm_fat2<<<1280, 256, 0, stream>>>(Ak, Ek, bk, Kt, Eout, T1T, Ecomb);
    // projV standalone
    gemm2<512, 2, 64><<<1024, 256, 0, stream>>>(Av, Ev, bv, Vt);

    // combined bias: bv2 = (bint*Efin^T + bfin)*Eout^T + bout
    matvec_E<<<512, 256, 0, stream>>>(bint, Efin, bfin, bv1);
    matvec_E<<<512, 256, 0, stream>>>(bv1,  Eout, bout, bv2);

    spectral3<<<4096, 256, 0, stream>>>(Qt, Kt, Vt, alpha, gws, pht);

    dim3 gt(64, 64, 4);
    transpose_k<<<gt, dim3(32, 8), 0, stream>>>(Vt, attn);

    // single fused trailing linear
    gemm2<2048, 1, 64><<<1024, 256, 0, stream>>>(attn, Ecomb, bv2, (float*)d_out);
}

// Round 12
// 384.547 us; speedup vs baseline: 1.3165x; 1.0371x over previous
//
#include <hip/hip_runtime.h>
#include <hip/hip_bf16.h>
#include <cstdint>

typedef unsigned short u16;
typedef u16  u16x8 __attribute__((ext_vector_type(8)));
typedef short s16x8 __attribute__((ext_vector_type(8)));
typedef float f32x4 __attribute__((ext_vector_type(4)));

#define PI_F 3.14159265358979323846f
#define PD(i) ((i) + 3 * ((i) >> 5))

static __device__ __forceinline__ u16 f2bf(float f) {
    union { float f; unsigned u; } v; v.f = f;
    unsigned r = v.u + 0x7fffu + ((v.u >> 16) & 1u);
    return (u16)(r >> 16);
}
static __device__ __forceinline__ float bf2f(u16 h) {
    union { unsigned u; float f; } v; v.u = ((unsigned)h) << 16;
    return v.f;
}

__device__ __forceinline__ void gl_lds16(const u16* g, u16* l) {
    __builtin_amdgcn_global_load_lds(
        (const __attribute__((address_space(1))) unsigned int*)g,
        (__attribute__((address_space(3))) unsigned int*)l, 16, 0, 0);
}

// ---------------------------------------------------------------------------
// f32 -> bf16 convert, 3 tensors in one dispatch (blockIdx.y selects)
// ---------------------------------------------------------------------------
__global__ __launch_bounds__(256) void cvt3(const float* __restrict__ q,
                                            const float* __restrict__ k,
                                            const float* __restrict__ v,
                                            u16* __restrict__ out, int n8) {
    int i = blockIdx.x * 256 + threadIdx.x;
    if (i >= n8) return;
    const float* in = (blockIdx.y == 0) ? q : (blockIdx.y == 1) ? k : v;
    u16* o = out + (size_t)blockIdx.y * 8192 * 512;
    float4 a = ((const float4*)in)[2 * i];
    float4 b = ((const float4*)in)[2 * i + 1];
    u16x8 vv;
    vv[0] = f2bf(a.x); vv[1] = f2bf(a.y); vv[2] = f2bf(a.z); vv[3] = f2bf(a.w);
    vv[4] = f2bf(b.x); vv[5] = f2bf(b.y); vv[6] = f2bf(b.z); vv[7] = f2bf(b.w);
    ((u16x8*)o)[i] = vv;
}

// ---------------------------------------------------------------------------
// Expand quaternion weights (3 per dispatch via blockIdx.y)
// ---------------------------------------------------------------------------
template<int LOGK>
__global__ void build_E3(const float* __restrict__ W0, const float* __restrict__ W1,
                         const float* __restrict__ W2, u16* __restrict__ E0,
                         u16* __restrict__ E1, u16* __restrict__ E2) {
    const int K = 1 << LOGK;
    int idx = blockIdx.x * 256 + threadIdx.x;
    if (idx >= (2048 << LOGK)) return;
    const float* W = (blockIdx.y == 0) ? W0 : (blockIdx.y == 1) ? W1 : W2;
    u16* E = (blockIdx.y == 0) ? E0 : (blockIdx.y == 1) ? E1 : E2;
    int n = idx >> LOGK, k = idx & (K - 1);
    int o = n >> 2, c = n & 3, i = k >> 2, cp = k & 3;
    const int   qm[4][4] = {{0,1,2,3},{1,0,3,2},{2,3,0,1},{3,2,1,0}};
    const float qs[4][4] = {{1.f,-1.f,-1.f,-1.f},{1.f,1.f,1.f,-1.f},
                            {1.f,-1.f,1.f,1.f},{1.f,1.f,-1.f,1.f}};
    int in_q = K >> 2;
    float w = W[(size_t)qm[c][cp] * 512 * in_q + (size_t)o * in_q + i] * qs[c][cp];
    E[idx] = f2bf(w);
}

// ---------------------------------------------------------------------------
// Tables: per-pass twiddle sub-tables + phases.
// ---------------------------------------------------------------------------
__global__ __launch_bounds__(256) void build_tabs(float2* __restrict__ gws,
                                                  float* __restrict__ ph) {
    int i = blockIdx.x * 256 + threadIdx.x;
    if (i < 682) {
        int off, lh;
        if (i < 2)        { off = 0;   lh = 1; }
        else if (i < 10)  { off = 2;   lh = 3; }
        else if (i < 42)  { off = 10;  lh = 5; }
        else if (i < 170) { off = 42;  lh = 7; }
        else              { off = 170; lh = 9; }
        int j = i - off;
        float a = (-PI_F) * (float)j / (float)(2 << lh);
        gws[i] = make_float2(cosf(a), sinf(a));
    }
    if (i <= 1024) {
        ph[i] = atanf(logf((float)i * (1.0f / 2048.0f) + 1e-6f));
    }
}

// ---------------------------------------------------------------------------
// Bias matvec: out[n] = sum_k v[k]*E[n][k] + badd[n]
// ---------------------------------------------------------------------------
__global__ __launch_bounds__(256) void matvec_E(const float* __restrict__ v,
                                                const u16* __restrict__ E,
                                                const float* __restrict__ badd,
                                                float* __restrict__ out) {
    int n    = (blockIdx.x * 256 + threadIdx.x) >> 6;
    int lane = threadIdx.x & 63;
    if (n >= 2048) return;
    const u16* row = E + (size_t)n * 2048;
    float s = 0.f;
    for (int j = lane; j < 2048; j += 64) s += v[j] * bf2f(row[j]);
#pragma unroll
    for (int o = 32; o; o >>= 1) s += __shfl_down(s, o, 64);
    if (lane == 0) out[n] = s + badd[n];
}

// ---------------------------------------------------------------------------
// bf16 MFMA GEMM body (m97 structure + XCD super-tiles). NBX=16, NBY=M/128.
// OUTMODE 0: bf16 [m][n]; 1: f32 [m][n]; 2: bf16 transposed [n][m]/[b][n][s]
// ---------------------------------------------------------------------------
template<int K, int OUTMODE, int NBY>
__device__ __forceinline__ void gemm_body(int bid, u16* As, u16* Bs,
                                          const u16* __restrict__ A,
                                          const u16* __restrict__ E,
                                          const float* __restrict__ bias,
                                          void* __restrict__ outp) {
    const int t    = threadIdx.x;
    const int lane = t & 63, wave = t >> 6;
    const int wr   = wave >> 1, wc = wave & 1;
    const int lr   = lane & 15, kg = lane >> 4;
    const int l7   = lr & 7;

    constexpr int SPX = (4 * (NBY / 4)) / 8;
    const int xcd = bid & 7, p = bid >> 3;
    const int st  = xcd * SPX + (p >> 4);
    const int w   = p & 15;
    const int bx  = (st & 3) * 4 + (w & 3);
    const int by  = (st >> 2) * 4 + (w >> 2);
    const int m0  = by * 128;
    const int n0  = bx * 128;

    f32x4 acc[4][4];
#pragma unroll
    for (int i = 0; i < 4; ++i)
#pragma unroll
        for (int j = 0; j < 4; ++j) acc[i][j] = (f32x4){0.f, 0.f, 0.f, 0.f};

    const int arow = wr * 64 + lr;
    const int brow = wc * 64 + lr;

    for (int k0 = 0; k0 < K; k0 += 64) {
#pragma unroll
        for (int c = 0; c < 4; ++c) {
            int idx = t + c * 256;
            int row = idx >> 3, sl = idx & 7;
            int gsl = sl ^ (row & 7);
            gl_lds16(A + (size_t)(m0 + row) * K + k0 + gsl * 8, &As[idx * 8]);
            gl_lds16(E + (size_t)(n0 + row) * K + k0 + gsl * 8, &Bs[idx * 8]);
        }
        __syncthreads();
#pragma unroll
        for (int ks = 0; ks < 2; ++ks) {
            const int slot = (ks * 4 + kg) ^ l7;
            s16x8 av[4], bv[4];
#pragma unroll
            for (int mi = 0; mi < 4; ++mi)
                av[mi] = *(const s16x8*)&As[(arow + mi * 16) * 64 + slot * 8];
#pragma unroll
            for (int ni = 0; ni < 4; ++ni)
                bv[ni] = *(const s16x8*)&Bs[(brow + ni * 16) * 64 + slot * 8];
#pragma unroll
            for (int mi = 0; mi < 4; ++mi)
#pragma unroll
                for (int ni = 0; ni < 4; ++ni)
                    acc[mi][ni] = __builtin_amdgcn_mfma_f32_16x16x32_bf16(
                        av[mi], bv[ni], acc[mi][ni], 0, 0, 0);
        }
        __syncthreads();
    }

#pragma unroll
    for (int ni = 0; ni < 4; ++ni) {
        int n = n0 + wc * 64 + ni * 16 + lr;
        float bvl = bias ? bias[n] : 0.0f;
#pragma unroll
        for (int mi = 0; mi < 4; ++mi) {
#pragma unroll
            for (int r = 0; r < 4; ++r) {
                int m = m0 + wr * 64 + mi * 16 + kg * 4 + r;
                float val = acc[mi][ni][r] + bvl;
                if constexpr (OUTMODE == 0) {
                    ((u16*)outp)[(size_t)m * 2048 + n] = f2bf(val);
                } else if constexpr (OUTMODE == 1) {
                    ((float*)outp)[(size_t)m * 2048 + n] = val;
                } else {
                    int b = m >> 11, s = m & 2047;
                    ((u16*)outp)[((size_t)b * 2048 + n) * 2048 + s] = f2bf(val);
                }
            }
        }
    }
}

template<int K, int OUTMODE, int NBY>
__global__ __launch_bounds__(256) void gemm2(const u16* __restrict__ A,
                                             const u16* __restrict__ E,
                                             const float* __restrict__ bias,
                                             void* __restrict__ outp) {
    __shared__ u16 As[128 * 64];
    __shared__ u16 Bs[128 * 64];
    gemm_body<K, OUTMODE, NBY>(blockIdx.x, As, Bs, A, E, bias, outp);
}

// Fat kernel 1: combine1 (Efin*EintT -> T1T) + projQ
__global__ __launch_bounds__(256) void gemm_fat1(const u16* __restrict__ Aq,
                                                 const u16* __restrict__ Eq,
                                                 const float* __restrict__ bq,
                                                 void* __restrict__ Qt,
                                                 const u16* __restrict__ Efin,
                                                 const u16* __restrict__ EintT,
                                                 void* __restrict__ T1T) {
    __shared__ u16 As[128 * 64];
    __shared__ u16 Bs[128 * 64];
    int bid = blockIdx.x;
    if (bid < 256)
        gemm_body<2048, 2, 16>(bid, As, Bs, Efin, EintT, nullptr, T1T);
    else
        gemm_body<512, 2, 64>(bid - 256, As, Bs, Aq, Eq, bq, Qt);
}

// Fat kernel 2: combine2 (Eout*T1T -> Ecomb) + projK
__global__ __launch_bounds__(256) void gemm_fat2(const u16* __restrict__ Ak,
                                                 const u16* __restrict__ Ek,
                                                 const float* __restrict__ bk,
                                                 void* __restrict__ Kt,
                                                 const u16* __restrict__ Eout,
                                                 const u16* __restrict__ T1T,
                                                 void* __restrict__ Ecomb) {
    __shared__ u16 As[128 * 64];
    __shared__ u16 Bs[128 * 64];
    int bid = blockIdx.x;
    if (bid < 256)
        gemm_body<2048, 0, 16>(bid, As, Bs, Eout, T1T, nullptr, Ecomb);
    else
        gemm_body<512, 2, 64>(bid - 256, As, Bs, Ak, Ek, bk, Kt);
}

// ---------------------------------------------------------------------------
// In-place FFT, bitrev input -> natural output. Radix-2 + radix-4 passes.
// ---------------------------------------------------------------------------
template<int LH, int OFF>
__device__ __forceinline__ void r4pass(float* re, float* im,
                                       const float2* __restrict__ wt, int t) {
    constexpr int h = 1 << LH;
    __syncthreads();
#pragma unroll
    for (int u = 0; u < 2; ++u) {
        int vidx = t + u * 256;
        int j = vidx & (h - 1);
        int i0 = ((vidx >> LH) << (LH + 2)) | j;
        float2 w2 = wt[OFF + j];
        float w1r = w2.x * w2.x - w2.y * w2.y;
        float w1i = 2.f * w2.x * w2.y;
        float w3r = w2.y, w3i = -w2.x;
        int p0 = PD(i0), p1 = PD(i0 + h), p2 = PD(i0 + 2 * h), p3 = PD(i0 + 3 * h);
        float ar = re[p0], ai = im[p0];
        float br = re[p1], bi = im[p1];
        float cr = re[p2], ci = im[p2];
        float dr = re[p3], di = im[p3];
        float tbr = w1r * br - w1i * bi, tbi = w1r * bi + w1i * br;
        float tdr = w1r * dr - w1i * di, tdi = w1r * di + w1i * dr;
        float a1r = ar + tbr, a1i = ai + tbi;
        float b1r = ar - tbr, b1i = ai - tbi;
        float c1r = cr + tdr, c1i = ci + tdi;
        float d1r = cr - tdr, d1i = ci - tdi;
        float tcr = w2.x * c1r - w2.y * c1i, tci = w2.x * c1i + w2.y * c1r;
        float ter = w3r * d1r - w3i * d1i, tei = w3r * d1i + w3i * d1r;
        re[p0] = a1r + tcr; im[p0] = a1i + tci;
        re[p2] = a1r - tcr; im[p2] = a1i - tci;
        re[p1] = b1r + ter; im[p1] = b1i + tei;
        re[p3] = b1r - ter; im[p3] = b1i - tei;
    }
}

__device__ void fft2048(float* re, float* im, const float2* __restrict__ wt, int t) {
    __syncthreads();
#pragma unroll
    for (int u = 0; u < 4; ++u) {
        int i0 = 2 * (t + u * 256);
        int p0 = PD(i0), p1 = p0 + 1;
        float ar = re[p0], ai = im[p0];
        float br = re[p1], bi = im[p1];
        re[p0] = ar + br; im[p0] = ai + bi;
        re[p1] = ar - br; im[p1] = ai - bi;
    }
    r4pass<1, 0>(re, im, wt, t);
    r4pass<3, 2>(re, im, wt, t);
    r4pass<5, 10>(re, im, wt, t);
    r4pass<7, 42>(re, im, wt, t);
    r4pass<9, 170>(re, im, wt, t);
    __syncthreads();
}

// ---------------------------------------------------------------------------
// Spectral body: 2 channels, packed FFTs; writes WEIGHTS to Wt (no V access).
// ---------------------------------------------------------------------------
__device__ void spectral_body(int sbid, float* zre, float* zim, float2* wt,
                              const u16* __restrict__ Qt,
                              const u16* __restrict__ Kt,
                              u16* __restrict__ Wt,
                              const float* __restrict__ alpha,
                              const float2* __restrict__ gws,
                              const float* __restrict__ gph) {
    const int t  = threadIdx.x;
    const int b  = sbid >> 10;
    const int cp = sbid & 1023;
    const int c0 = cp * 2;
    const size_t base0 = ((size_t)b * 2048 + c0) * 2048;
    const size_t base1 = base0 + 2048;

    for (int i = t; i < 682; i += 256) wt[i] = gws[i];

    float ph[4];
    float PH1r[4], PH1i[4], PH2r[4], PH2i[4];
    float ph24 = 0.f, PH24_1 = 0.f, PH24_2 = 0.f;

#pragma unroll
    for (int ch = 0; ch < 2; ++ch) {
        const size_t base = ch ? base1 : base0;
        const u16* Qp = Qt + base;
        const u16* Kp = Kt + base;
        __syncthreads();
#pragma unroll
        for (int u = 0; u < 8; ++u) {
            int s = t + u * 256;
            int r = __brev((unsigned)s) >> 21;
            zre[PD(r)] = bf2f(Qp[s]);
            zim[PD(r)] = bf2f(Kp[s]);
        }
        fft2048(zre, zim, wt, t);
        const float ac = alpha[c0 + ch];
#pragma unroll
        for (int u = 0; u < 4; ++u) {
            int k = t + u * 256;
            int m = (2048 - k) & 2047;
            float ar = zre[PD(k)], ai = zim[PD(k)];
            float br = zre[PD(m)], bi = zim[PD(m)];
            float qr = 0.5f * (ar + br), qi = 0.5f * (ai - bi);
            float kr = 0.5f * (ai + bi), ki = 0.5f * (br - ar);
            float cr = qr * kr + qi * ki;
            float ci = qi * kr - qr * ki;
            if (ch == 0) ph[u] = gph[min(k, 2048 - k)];
            float fr, fi;
            __sincosf(ph[u] * ac, &fi, &fr);
            float Pkr = cr * fr - ci * fi, Pki = cr * fi + ci * fr;
            float qr2 = 0.5f * (br + ar), qi2 = 0.5f * (bi - ai);
            float kr2 = 0.5f * (bi + ai), ki2 = 0.5f * (ar - br);
            float cr2 = qr2 * kr2 + qi2 * ki2;
            float ci2 = qi2 * kr2 - qr2 * ki2;
            float Pmr = cr2 * fr - ci2 * fi, Pmi = cr2 * fi + ci2 * fr;
            float hr = 0.5f * (Pkr + Pmr), hi = 0.5f * (Pki - Pmi);
            if (ch == 0) { PH1r[u] = hr; PH1i[u] = hi; }
            else         { PH2r[u] = hr; PH2i[u] = hi; }
        }
        if (t == 0) {
            float ar = zre[PD(1024)], ai = zim[PD(1024)];
            float cr = ar * ai;
            if (ch == 0) ph24 = gph[1024];
            float fr, fi;
            __sincosf(ph24 * ac, &fi, &fr);
            if (ch == 0) PH24_1 = cr * fr; else PH24_2 = cr * fr;
        }
    }

    __syncthreads();
#pragma unroll
    for (int u = 0; u < 4; ++u) {
        int k = t + u * 256;
        int m = (2048 - k) & 2047;
        int rk = __brev((unsigned)k) >> 21;
        int rm = __brev((unsigned)m) >> 21;
        zre[PD(rk)] = PH1r[u] - PH2i[u];
        zim[PD(rk)] = PH1i[u] + PH2r[u];
        zre[PD(rm)] = PH1r[u] + PH2i[u];
        zim[PD(rm)] = PH2r[u] - PH1i[u];
    }
    if (t == 0) {
        zre[PD(1)] = PH24_1;
        zim[PD(1)] = PH24_2;
    }
    fft2048(zre, zim, wt, t);

#pragma unroll
    for (int u = 0; u < 8; ++u) {
        int s = t + u * 256;
        int j = (2048 - s) & 2047;
        Wt[base0 + s] = f2bf(zre[PD(j)] * (1.0f / 2048.0f));
        Wt[base1 + s] = f2bf(zim[PD(j)] * (1.0f / 2048.0f));
    }
}

// Fat kernel: spectral (4096 blocks) + projV (1024 blocks), interleaved 4:1.
__global__ __launch_bounds__(256) void fat_specv(const u16* __restrict__ Qt,
                                                 const u16* __restrict__ Kt,
                                                 u16* __restrict__ Wt,
                                                 const float* __restrict__ alpha,
                                                 const float2* __restrict__ gws,
                                                 const float* __restrict__ gph,
                                                 const u16* __restrict__ Av,
                                                 const u16* __restrict__ Ev,
                                                 const float* __restrict__ bvb,
                                                 void* __restrict__ Vt) {
    __shared__ __align__(16) char smem[32768];
    int bid = blockIdx.x;
    if (bid % 5 == 4) {
        gemm_body<512, 2, 64>(bid / 5, (u16*)smem, (u16*)(smem + 16384),
                              Av, Ev, bvb, Vt);
    } else {
        int sbid = (bid / 5) * 4 + (bid % 5);
        spectral_body(sbid, (float*)smem, (float*)(smem + 8960),
                      (float2*)(smem + 17920), Qt, Kt, Wt, alpha, gws, gph);
    }
}

// ---------------------------------------------------------------------------
// Plain transpose (EintT) and fused multiply-transpose (attn = (W .* V)^T)
// ---------------------------------------------------------------------------
__global__ __launch_bounds__(256) void transpose_k(const u16* __restrict__ in,
                                                   u16* __restrict__ out) {
    __shared__ u16 tile[32][33];
    int b = blockIdx.z;
    int c0 = blockIdx.x * 32, s0 = blockIdx.y * 32;
    int tx = threadIdx.x, ty = threadIdx.y;
#pragma unroll
    for (int dy = 0; dy < 32; dy += 8)
        tile[ty + dy][tx] = in[((size_t)b * 2048 + c0 + ty + dy) * 2048 + s0 + tx];
    __syncthreads();
#pragma unroll
    for (int dy = 0; dy < 32; dy += 8)
        out[((size_t)b * 2048 + s0 + ty + dy) * 2048 + c0 + tx] = tile[tx][ty + dy];
}

__global__ __launch_bounds__(256) void transpose_mul(const u16* __restrict__ W,
                                                     const u16* __restrict__ V,
                                                     u16* __restrict__ out) {
    __shared__ u16 tile[32][33];
    int b = blockIdx.z;
    int c0 = blockIdx.x * 32, s0 = blockIdx.y * 32;
    int tx = threadIdx.x, ty = threadIdx.y;
#pragma unroll
    for (int dy = 0; dy < 32; dy += 8) {
        size_t idx = ((size_t)b * 2048 + c0 + ty + dy) * 2048 + s0 + tx;
        tile[ty + dy][tx] = f2bf(bf2f(W[idx]) * bf2f(V[idx]));
    }
    __syncthreads();
#pragma unroll
    for (int dy = 0; dy < 32; dy += 8)
        out[((size_t)b * 2048 + s0 + ty + dy) * 2048 + c0 + tx] = tile[tx][ty + dy];
}

// ---------------------------------------------------------------------------
extern "C" void kernel_launch(void* const* d_in, const int* in_sizes, int n_in,
                              void* d_out, int out_size, void* d_ws, size_t ws_size,
                              hipStream_t stream) {
    const float* query = (const float*)d_in[0];
    const float* key   = (const float*)d_in[1];
    const float* value = (const float*)d_in[2];
    const float* Wq    = (const float*)d_in[3];
    const float* bq    = (const float*)d_in[4];
    const float* Wk    = (const float*)d_in[5];
    const float* bk    = (const float*)d_in[6];
    const float* Wv    = (const float*)d_in[7];
    const float* bv    = (const float*)d_in[8];
    const float* alpha = (const float*)d_in[9];
    const float* Wint  = (const float*)d_in[10];
    const float* bint  = (const float*)d_in[11];
    const float* Wfin  = (const float*)d_in[12];
    const float* bfin  = (const float*)d_in[13];
    const float* Wout  = (const float*)d_in[14];
    const float* bout  = (const float*)d_in[15];

    char* ws = (char*)d_ws;
    size_t off = 0;
    auto alloc = [&](size_t bytes) -> void* {
        void* p = ws + off;
        off += (bytes + 255) & ~(size_t)255;
        return p;
    };
    u16* Eq   = (u16*)alloc((size_t)2048 * 512 * 2);
    u16* Ek   = (u16*)alloc((size_t)2048 * 512 * 2);
    u16* Ev   = (u16*)alloc((size_t)2048 * 512 * 2);
    u16* Eint = (u16*)alloc((size_t)2048 * 2048 * 2);   // becomes Ecomb
    u16* Efin = (u16*)alloc((size_t)2048 * 2048 * 2);   // Wt reuses Efin..T1T
    u16* Eout = (u16*)alloc((size_t)2048 * 2048 * 2);
    u16* EintT= (u16*)alloc((size_t)2048 * 2048 * 2);
    u16* T1T  = (u16*)alloc((size_t)2048 * 2048 * 2);
    u16* Qt   = (u16*)alloc((size_t)4 * 2048 * 2048 * 2);
    u16* Kt   = (u16*)alloc((size_t)4 * 2048 * 2048 * 2);
    u16* Vt   = (u16*)alloc((size_t)4 * 2048 * 2048 * 2);
    u16* attn = (u16*)alloc((size_t)8192 * 2048 * 2);
    float2* gws = (float2*)alloc(682 * 8);
    float*  pht = (float*)alloc(1025 * 4);
    float*  bv1 = (float*)alloc(2048 * 4);
    float*  bv2 = (float*)alloc(2048 * 4);
    u16* Ecomb = Eint;            // Eint dead (as weights) after EintT built
    u16* Wt    = Efin;            // Efin/Eout/EintT/T1T dead after matvecs: 32 MiB
    u16* Aq = attn;
    u16* Ak = attn + (size_t)8192 * 512;
    u16* Av = attn + (size_t)8192 * 1024;

    const int n8 = 8192 * 512 / 8;
    cvt3<<<dim3((n8 + 255) / 256, 3), 256, 0, stream>>>(query, key, value, Aq, n8);
    build_tabs<<<5, 256, 0, stream>>>(gws, pht);
    build_E3<9><<<dim3(4096, 3), 256, 0, stream>>>(Wq, Wk, Wv, Eq, Ek, Ev);
    build_E3<11><<<dim3(16384, 3), 256, 0, stream>>>(Wint, Wfin, Wout, Eint, Efin, Eout);

    dim3 gt1(64, 64, 1);
    transpose_k<<<gt1, dim3(32, 8), 0, stream>>>(Eint, EintT);

    gemm_fat1<<<1280, 256, 0, stream>>>(Aq, Eq, bq, Qt, Efin, EintT, T1T);
    gemm_fat2<<<1280, 256, 0, stream>>>(Ak, Ek, bk, Kt, Eout, T1T, Ecomb);

    // combined bias (consumes Efin/Eout BEFORE Wt overwrites them)
    matvec_E<<<512, 256, 0, stream>>>(bint, Efin, bfin, bv1);
    matvec_E<<<512, 256, 0, stream>>>(bv1,  Eout, bout, bv2);

    // spectral weights + projV co-scheduled (independent block families)
    fat_specv<<<5120, 256, 0, stream>>>(Qt, Kt, Wt, alpha, gws, pht,
                                        Av, Ev, bv, Vt);

    // attn[(b,s)][c] = W[b][c][s] * V[b][c][s]
    dim3 gt(64, 64, 4);
    transpose_mul<<<gt, dim3(32, 8), 0, stream>>>(Wt, Vt, attn);

    // single fused trailing linear
    gemm2<2048, 1, 64><<<1024, 256, 0, stream>>>(attn, Ecomb, bv2, (float*)d_out);
}